// Round 3
// baseline (913.526 us; speedup 1.0000x reference)
//
#include <hip/hip_runtime.h>
#include <hip/hip_bf16.h>

using u16 = unsigned short;
using u32 = unsigned int;
typedef short short8 __attribute__((ext_vector_type(8)));
typedef float f32x4 __attribute__((ext_vector_type(4)));

#define B_  2
#define S_  2048
#define E_  768
#define BS_ 4096

#define L2E_ 1.44269504088896f
#define FML2_ 17.3123404906676f   // 12.0 * log2(e) fixed softmax stabilizer

__device__ __forceinline__ u16 f2bf(float f) {
  __hip_bfloat16 h = __float2bfloat16(f);
  return *reinterpret_cast<u16*>(&h);
}

__device__ __forceinline__ u32 pk2(float a, float b) {
  return (u32)f2bf(a) | ((u32)f2bf(b) << 16);
}

// async global->LDS, 16B per lane. LDS dest must be wave-uniform base + lane*16.
__device__ __forceinline__ void gld16(const void* g, void* l) {
  __builtin_amdgcn_global_load_lds(
      (const __attribute__((address_space(1))) u32*)g,
      (__attribute__((address_space(3))) u32*)l, 16, 0, 0);
}

// ---------------- conversion / misc kernels ----------------

__global__ __launch_bounds__(256) void conv_x_k(const float* __restrict__ x,
                                                u16* __restrict__ xb, int n4) {
  int i = blockIdx.x * 256 + threadIdx.x;
  if (i >= n4) return;
  float4 v = reinterpret_cast<const float4*>(x)[i];
  reinterpret_cast<uint2*>(xb)[i] = make_uint2(pk2(v.x, v.y), pk2(v.z, v.w));
}

__global__ __launch_bounds__(256) void bias_k(
    const float* rqb, const float* rkb, const float* rvb,
    const float* cqb, const float* ckb, const float* cvb,
    const float* rob, const float* cob,
    const float* rcb, const float* ccb,
    float* bqkv, float* bproj) {
  int t = blockIdx.x * 256 + threadIdx.x;
  if (t < 4608) {
    int seg = t / 768, i = t - seg * 768;
    float v = 0.f;
    if      (seg == 0) v = rqb[i] + rcb[i];   // cultural bias folds into Q bias
    else if (seg == 1) v = rkb[i];
    else if (seg == 2) v = rvb[i];
    else if (seg == 3) v = cqb[i] + ccb[i];
    else if (seg == 4) v = ckb[i];
    else               v = cvb[i];
    bqkv[t] = v;
  } else {
    int u = t - 4608;
    if (u < 1536) bproj[u] = (u < 768) ? rob[u] : cob[u - 768];
  }
}

struct TP {
  const float* src[9];
  u16* dst[9];
  int rows[9];
};

// dst[c][r] = bf16(src[r][c]); src is [rows][768]
__global__ __launch_bounds__(256) void transpose_k(TP p) {
  int mi = blockIdx.z;
  int rows = p.rows[mi];
  int r0 = blockIdx.y * 32;
  if (r0 >= rows) return;
  int c0 = blockIdx.x * 32;
  const float* src = p.src[mi];
  u16* dst = p.dst[mi];
  __shared__ float t[32][33];
  int tx = threadIdx.x & 31, ty = threadIdx.x >> 5;
#pragma unroll
  for (int d = 0; d < 4; ++d) {
    int r = ty + d * 8;
    t[r][tx] = src[(size_t)(r0 + r) * 768 + c0 + tx];
  }
  __syncthreads();
#pragma unroll
  for (int d = 0; d < 4; ++d) {
    int c = ty + d * 8;
    dst[(size_t)(c0 + c) * rows + r0 + tx] = f2bf(t[tx][c]);
  }
}

// ============ transposed GEMM: computes C^T, i.e. C[row=M][col=N] with
// A[M][K], BT[N][K]; lane's 4 acc values are CONSECUTIVE M-rows -> packed
// 8B stores. MODE 0: PROJ (bf16 -> Cout[col*ldc+row], m-split A select)
// MODE 1: FINAL (fp32 float4 -> Cout[col*ldc+row])
// MODE 2: QKVT routing (M=feature, N=token) ============

template<int MODE>
__global__ __launch_bounds__(256) void gemm_t_k(
    const u16* __restrict__ A, int lda,
    const u16* __restrict__ BT, int ldb,
    const float* __restrict__ bias, int K,
    const u16* __restrict__ A2, int msplit, int bofs,
    void* __restrict__ Cout, int ldc,
    u16* __restrict__ Qr, u16* __restrict__ Kr, u16* __restrict__ Vtr,
    u16* __restrict__ Qc, u16* __restrict__ Kc, u16* __restrict__ Vtc) {
  __shared__ u16 lA[128 * 32];
  __shared__ u16 lB[128 * 32];
  const int tid = threadIdx.x, w = tid >> 6, lane = tid & 63;
  const int quad = lane >> 4, l15 = lane & 15;
  const int m0 = blockIdx.y * 128, n0 = blockIdx.x * 128;
  if (msplit && m0 >= msplit) { A = A2 - (size_t)msplit * lda; BT += bofs; }

  const f32x4 z4 = {0.f, 0.f, 0.f, 0.f};
  f32x4 acc[4][4];
#pragma unroll
  for (int i = 0; i < 4; ++i)
#pragma unroll
    for (int j = 0; j < 4; ++j) acc[i][j] = z4;

  const int sr = w * 32 + (lane >> 2);
  const int scp = lane & 3;

  for (int kt = 0; kt < K; kt += 32) {
    int r1 = sr, r2 = sr + 16;
    int c1 = (scp - (r1 >> 2)) & 3;
    int c2 = (scp - (r2 >> 2)) & 3;
    gld16(A + (size_t)(m0 + r1) * lda + kt + c1 * 8, &lA[r1 * 32 + scp * 8]);
    gld16(A + (size_t)(m0 + r2) * lda + kt + c2 * 8, &lA[r2 * 32 + scp * 8]);
    gld16(BT + (size_t)(n0 + r1) * ldb + kt + c1 * 8, &lB[r1 * 32 + scp * 8]);
    gld16(BT + (size_t)(n0 + r2) * ldb + kt + c2 * 8, &lB[r2 * 32 + scp * 8]);
    __syncthreads();
    short8 af[4], bg[4];
#pragma unroll
    for (int i = 0; i < 4; ++i) {
      int r = (w >> 1) * 64 + i * 16 + l15;
      af[i] = *reinterpret_cast<const short8*>(&lA[r * 32 + ((quad + (r >> 2)) & 3) * 8]);
    }
#pragma unroll
    for (int j = 0; j < 4; ++j) {
      int r = (w & 1) * 64 + j * 16 + l15;
      bg[j] = *reinterpret_cast<const short8*>(&lB[r * 32 + ((quad + (r >> 2)) & 3) * 8]);
    }
#pragma unroll
    for (int i = 0; i < 4; ++i)
#pragma unroll
      for (int j = 0; j < 4; ++j)
        acc[i][j] = __builtin_amdgcn_mfma_f32_16x16x32_bf16(af[i], bg[j], acc[i][j], 0, 0, 0);
    __syncthreads();
  }

  const int seg = (MODE == 2) ? (m0 / 768) : 0;
#pragma unroll
  for (int i = 0; i < 4; ++i) {
    int f = m0 + (w >> 1) * 64 + i * 16 + quad * 4;   // M-row base (4 consecutive)
    float4 b4 = *reinterpret_cast<const float4*>(bias + f);
#pragma unroll
    for (int j = 0; j < 4; ++j) {
      int t = n0 + (w & 1) * 64 + j * 16 + l15;        // N-col
      float v0 = acc[i][j][0] + b4.x;
      float v1 = acc[i][j][1] + b4.y;
      float v2 = acc[i][j][2] + b4.z;
      float v3 = acc[i][j][3] + b4.w;
      if (MODE == 0) {
        *reinterpret_cast<uint2*>((u16*)Cout + (size_t)t * ldc + f) =
            make_uint2(pk2(v0, v1), pk2(v2, v3));
      } else if (MODE == 1) {
        *reinterpret_cast<float4*>((float*)Cout + (size_t)t * ldc + f) =
            make_float4(v0, v1, v2, v3);
      } else {
        int b = t >> 11, s = t & 2047;
        int fs = f - seg * 768;
        if (seg == 0) {
          int h = fs >> 7, d = fs & 127;
          *reinterpret_cast<uint2*>(Qr + ((size_t)(b * 6 + h) * 2048 + s) * 128 + d) =
              make_uint2(pk2(v0, v1), pk2(v2, v3));
        } else if (seg == 1) {
          int h = fs >> 7, d = fs & 127;
          *reinterpret_cast<uint2*>(Kr + ((size_t)(b * 6 + h) * 2048 + s) * 128 + d) =
              make_uint2(pk2(v0, v1), pk2(v2, v3));
        } else if (seg == 2) {
          int h = fs >> 7, d = fs & 127;
          u16* vp = Vtr + ((size_t)(b * 6 + h) * 128 + d) * 2048 + s;
          vp[0] = f2bf(v0); vp[2048] = f2bf(v1); vp[4096] = f2bf(v2); vp[6144] = f2bf(v3);
        } else if (seg == 3) {
          int h = fs / 384, d = fs - h * 384;
          *reinterpret_cast<uint2*>(Qc + ((size_t)(b * 2 + h) * 2048 + s) * 384 + d) =
              make_uint2(pk2(v0, v1), pk2(v2, v3));
        } else if (seg == 4) {
          int h = fs / 384, d = fs - h * 384;
          *reinterpret_cast<uint2*>(Kc + ((size_t)(b * 2 + h) * 2048 + s) * 384 + d) =
              make_uint2(pk2(v0, v1), pk2(v2, v3));
        } else {
          int h = fs / 384, d = fs - h * 384;
          u16* vp = Vtc + ((size_t)(b * 2 + h) * 384 + d) * 2048 + s;
          vp[0] = f2bf(v0); vp[2048] = f2bf(v1); vp[4096] = f2bf(v2); vp[6144] = f2bf(v3);
        }
      }
    }
  }
}

// ---------------- fused attention v3 ----------------
// One block = one (head-config, q-tile), FULL k-range (KR=1) -> in-block
// normalization, direct bf16 AO write (no OP/Ls/red round-trip).
// 1-D grid with XCD-aware mapping: xcd = bid&7; each XCD hosts 3 head-configs
// x 16 q-tiles (stride-8 zcfg interleaves regular/cultural for load balance);
// K/V/Q staging re-reads become XCD-L2 hits. cmask float4 loads hoisted into
// registers during slice-2 staging (latency hidden under QK MFMA).
__device__ __forceinline__ void stage128(const u16* __restrict__ src, int srcStride,
                                         u16* buf, int w, int lane) {
  const int rl = lane >> 4;          // row within 4-row group
  const int cg0 = lane & 15;         // 16B col-group
#pragma unroll
  for (int it = 0; it < 8; ++it) {
    int r0 = w * 32 + it * 4;
    int row = r0 + rl;
    int cg = cg0 ^ (row & 7);        // pre-swizzled source column
    gld16(src + (size_t)row * srcStride + cg * 8, buf + r0 * 128 + lane * 8);
  }
}

__device__ __forceinline__ short8 rdfrag(const u16* buf, int r, int kt, int quad) {
  int slot = (((kt >> 3) + quad) ^ (r & 7)) & 15;
  return *reinterpret_cast<const short8*>(buf + r * 128 + slot * 8);
}

__global__ __launch_bounds__(256, 2) void attn_fused3_k(
    const u16* __restrict__ Qr, const u16* __restrict__ Kr,
    const u16* __restrict__ Vtr,
    const u16* __restrict__ Qc, const u16* __restrict__ Kc,
    const u16* __restrict__ Vtc,
    u16* __restrict__ AO,
    const float* __restrict__ am, const float* __restrict__ cmask,
    float sReg, float sCul) {
  const int bid = blockIdx.x;                 // 0..383
  const int xcd = bid & 7;
  const int j8 = bid >> 3;                    // 0..47
  const int zcfg = xcd + (j8 >> 4) * 8;       // 0..23, stride-8 per XCD
  const int qt0 = (j8 & 15) * 128;

  const u16 *Q, *K, *Vt;
  const float* cm = nullptr;
  float scl;
  int b, colbase, vrow0;
  bool reg;
  if (zcfg < 12) {
    reg = true;
    const int gz = zcfg;
    Q  = Qr  + (size_t)gz * S_ * 128;
    K  = Kr  + (size_t)gz * S_ * 128;
    Vt = Vtr + (size_t)gz * 128 * S_;
    b = gz / 6; scl = sReg;
    colbase = (gz % 6) * 128; vrow0 = 0;
  } else {
    reg = false;
    const int c = zcfg - 12;
    const int hc = c / 3, y = c - hc * 3;     // cultural head-config, V d-slice
    Q  = Qc  + (size_t)hc * S_ * 384;
    K  = Kc  + (size_t)hc * S_ * 384;
    Vt = Vtc + (size_t)hc * 384 * S_;
    b = hc >> 1; scl = sCul;
    cm = cmask + (size_t)b * S_ * S_;
    vrow0 = y * 128;
    colbase = 768 + (hc & 1) * 384 + vrow0;
  }

  __shared__ __align__(16) u16 bufA[128 * 128];   // K-slice -> P; prologue Q; tail lSum
  __shared__ __align__(16) u16 bufB[128 * 128];   // Q-slice (cul) / V-tile

  const int tid = threadIdx.x, w = tid >> 6, lane = tid & 63;
  const int quad = lane >> 4, l15 = lane & 15;
  const int rAb = (w >> 1) * 64 + l15;            // A-frag row base (m)
  const int rBb = (w & 1) * 64 + l15;             // B-frag row base (n)
  const float* amb = am + b * S_;

  const f32x4 z4 = {0.f, 0.f, 0.f, 0.f};
  f32x4 accO[4][4];
#pragma unroll
  for (int i = 0; i < 4; ++i)
#pragma unroll
    for (int j = 0; j < 4; ++j) accO[i][j] = z4;
  float lsum[4] = {0.f, 0.f, 0.f, 0.f};

  // regular: Q fragments to registers once (stage via bufA)
  short8 qf[4][4];
  if (reg) {
    stage128(Q + (size_t)qt0 * 128, 128, bufA, w, lane);
    __syncthreads();
#pragma unroll
    for (int kt4 = 0; kt4 < 4; ++kt4)
#pragma unroll
      for (int j = 0; j < 4; ++j)
        qf[kt4][j] = rdfrag(bufA, rBb + j * 16, kt4 * 32, quad);
    __syncthreads();
  }

  for (int ck = 0; ck < 16; ++ck) {
    const int kc = ck * 128;
    f32x4 accS[4][4];
#pragma unroll
    for (int i = 0; i < 4; ++i)
#pragma unroll
      for (int j = 0; j < 4; ++j) accS[i][j] = z4;

    // hoist attention-mask row for this k-chunk (all paths)
    float4 amr[4];
#pragma unroll
    for (int i = 0; i < 4; ++i)
      amr[i] = *reinterpret_cast<const float4*>(
          amb + kc + (w >> 1) * 64 + i * 16 + quad * 4);

    float4 cmr[4][4];
    if (reg) {
      // stage K-chunk + V-chunk together, then barrier-free QK (Q in regs)
      stage128(K + (size_t)kc * 128, 128, bufA, w, lane);
      stage128(Vt + (size_t)vrow0 * S_ + kc, S_, bufB, w, lane);
      __syncthreads();
#pragma unroll
      for (int kt = 0; kt < 128; kt += 32) {
        short8 af[4];
#pragma unroll
        for (int i = 0; i < 4; ++i) af[i] = rdfrag(bufA, rAb + i * 16, kt, quad);
#pragma unroll
        for (int i = 0; i < 4; ++i)
#pragma unroll
          for (int j = 0; j < 4; ++j)
            accS[i][j] = __builtin_amdgcn_mfma_f32_16x16x32_bf16(
                af[i], qf[kt >> 5][j], accS[i][j], 0, 0, 0);
      }
      __syncthreads();    // bufA consumed -> P may overwrite
    } else {
      // cultural: 3 d-slices of K-sub + Q-sub; cm loads issued at slice 2
      for (int s = 0; s < 3; ++s) {
        stage128(K + (size_t)kc * 384 + s * 128, 384, bufA, w, lane);
        stage128(Q + (size_t)qt0 * 384 + s * 128, 384, bufB, w, lane);
        if (s == 2) {
#pragma unroll
          for (int i = 0; i < 4; ++i) {
            const int kg = kc + (w >> 1) * 64 + i * 16 + quad * 4;
#pragma unroll
            for (int j = 0; j < 4; ++j) {
              const int ql = (w & 1) * 64 + j * 16 + l15;
              cmr[i][j] = *reinterpret_cast<const float4*>(
                  cm + (size_t)(qt0 + ql) * S_ + kg);
            }
          }
        }
        __syncthreads();
#pragma unroll
        for (int kt = 0; kt < 128; kt += 32) {
          short8 af[4], bg[4];
#pragma unroll
          for (int i = 0; i < 4; ++i) af[i] = rdfrag(bufA, rAb + i * 16, kt, quad);
#pragma unroll
          for (int j = 0; j < 4; ++j) bg[j] = rdfrag(bufB, rBb + j * 16, kt, quad);
#pragma unroll
          for (int i = 0; i < 4; ++i)
#pragma unroll
            for (int j = 0; j < 4; ++j)
              accS[i][j] = __builtin_amdgcn_mfma_f32_16x16x32_bf16(
                  af[i], bg[j], accS[i][j], 0, 0, 0);
        }
        __syncthreads();
      }
      // issue V loads early; latency hides under P epilogue
      stage128(Vt + (size_t)vrow0 * S_ + kc, S_, bufB, w, lane);
    }

    // ---------- P = exp2(accS*scl + masks) -> bufA (swizzled bf16) ----------
#pragma unroll
    for (int i = 0; i < 4; ++i) {
      const int kbl = (w >> 1) * 64 + i * 16 + quad * 4;   // 4 consecutive keys
      float pre0 = fmaf(amr[i].x, L2E_, -FML2_);
      float pre1 = fmaf(amr[i].y, L2E_, -FML2_);
      float pre2 = fmaf(amr[i].z, L2E_, -FML2_);
      float pre3 = fmaf(amr[i].w, L2E_, -FML2_);
      const int slot = (kbl >> 3);
#pragma unroll
      for (int j = 0; j < 4; ++j) {
        const int ql = (w & 1) * 64 + j * 16 + l15;
        float c0 = pre0, c1 = pre1, c2 = pre2, c3 = pre3;
        if (!reg) {
          c0 = fmaf(cmr[i][j].x, L2E_, c0);
          c1 = fmaf(cmr[i][j].y, L2E_, c1);
          c2 = fmaf(cmr[i][j].z, L2E_, c2);
          c3 = fmaf(cmr[i][j].w, L2E_, c3);
        }
        float p0 = exp2f(fmaf(accS[i][j][0], scl, c0));
        float p1 = exp2f(fmaf(accS[i][j][1], scl, c1));
        float p2 = exp2f(fmaf(accS[i][j][2], scl, c2));
        float p3 = exp2f(fmaf(accS[i][j][3], scl, c3));
        lsum[j] += (p0 + p1) + (p2 + p3);
        *reinterpret_cast<uint2*>(
            &bufA[ql * 128 + (slot ^ (ql & 7)) * 8 + (quad & 1) * 4]) =
            make_uint2(pk2(p0, p1), pk2(p2, p3));
      }
    }
    __syncthreads();    // P visible; V vmcnt drained

    // ---------- PV: accO[d][q] += V(bufB) . P(bufA)^T ----------
#pragma unroll
    for (int kt = 0; kt < 128; kt += 32) {
      short8 af[4], bg[4];
#pragma unroll
      for (int i = 0; i < 4; ++i) af[i] = rdfrag(bufB, rAb + i * 16, kt, quad);
#pragma unroll
      for (int j = 0; j < 4; ++j) bg[j] = rdfrag(bufA, rBb + j * 16, kt, quad);
#pragma unroll
      for (int i = 0; i < 4; ++i)
#pragma unroll
        for (int j = 0; j < 4; ++j)
          accO[i][j] = __builtin_amdgcn_mfma_f32_16x16x32_bf16(
              af[i], bg[j], accO[i][j], 0, 0, 0);
    }
    __syncthreads();    // buffers reusable next chunk
  }

  // ---------- full row sums -> invl ----------
  float* lSum = reinterpret_cast<float*>(bufA);   // bufA dead after last barrier
#pragma unroll
  for (int j = 0; j < 4; ++j) {
    float s = lsum[j];
    s += __shfl_xor(s, 16);
    s += __shfl_xor(s, 32);
    if (lane < 16) lSum[(w >> 1) * 128 + (w & 1) * 64 + j * 16 + lane] = s;
  }
  __syncthreads();
  float invl[4];
#pragma unroll
  for (int j = 0; j < 4; ++j) {
    const int ql = (w & 1) * 64 + j * 16 + l15;
    invl[j] = 1.f / (lSum[ql] + lSum[128 + ql]);
  }

  // ---------- normalize & store AO[token][feature] (bf16) ----------
#pragma unroll
  for (int i = 0; i < 4; ++i) {
    const int feat = colbase + (w >> 1) * 64 + i * 16 + quad * 4;
#pragma unroll
    for (int j = 0; j < 4; ++j) {
      const int qg = qt0 + (w & 1) * 64 + j * 16 + l15;
      float v0 = accO[i][j][0] * invl[j];
      float v1 = accO[i][j][1] * invl[j];
      float v2 = accO[i][j][2] * invl[j];
      float v3 = accO[i][j][3] * invl[j];
      *reinterpret_cast<uint2*>(AO + ((size_t)(b * S_ + qg)) * 1536 + feat) =
          make_uint2(pk2(v0, v1), pk2(v2, v3));
    }
  }
}

// ---------------- launcher ----------------

extern "C" void kernel_launch(void* const* d_in, const int* in_sizes, int n_in,
                              void* d_out, int out_size, void* d_ws, size_t ws_size,
                              hipStream_t stream) {
  const float* x     = (const float*)d_in[0];
  const float* cmask = (const float*)d_in[1];
  const float* amask = (const float*)d_in[2];
  const float* W[8]  = { (const float*)d_in[3], (const float*)d_in[4], (const float*)d_in[5],
                         (const float*)d_in[6], (const float*)d_in[7], (const float*)d_in[8],
                         (const float*)d_in[9], (const float*)d_in[10] };
  const float* rq_b = (const float*)d_in[11];
  const float* rk_b = (const float*)d_in[12];
  const float* rv_b = (const float*)d_in[13];
  const float* ro_b = (const float*)d_in[14];
  const float* cq_b = (const float*)d_in[15];
  const float* ck_b = (const float*)d_in[16];
  const float* cv_b = (const float*)d_in[17];
  const float* co_b = (const float*)d_in[18];
  const float* r_cb = (const float*)d_in[19];
  const float* c_cb = (const float*)d_in[20];
  const float* out_w = (const float*)d_in[21];
  const float* out_b = (const float*)d_in[22];

  char* p = (char*)d_ws;
  auto carve = [&](size_t bytes) -> void* {
    void* r = (void*)p;
    p += (bytes + 255) & ~(size_t)255;
    return r;
  };
  u16* Xb    = (u16*)carve((size_t)BS_ * E_ * 2);
  u16* WqkvT = (u16*)carve((size_t)4608 * 768 * 2);
  u16* roT   = (u16*)carve((size_t)768 * 768 * 2);
  u16* coT   = (u16*)carve((size_t)768 * 768 * 2);
  u16* outwT = (u16*)carve((size_t)768 * 1536 * 2);
  float* bqkv  = (float*)carve(4608 * 4);
  float* bproj = (float*)carve(1536 * 4);
  u16* Qr  = (u16*)carve((size_t)B_ * 6 * S_ * 128 * 2);
  u16* Kr  = (u16*)carve((size_t)B_ * 6 * S_ * 128 * 2);
  u16* Vtr = (u16*)carve((size_t)B_ * 6 * S_ * 128 * 2);
  u16* Qc  = (u16*)carve((size_t)B_ * 2 * S_ * 384 * 2);
  u16* Kc  = (u16*)carve((size_t)B_ * 2 * S_ * 384 * 2);
  u16* Vtc = (u16*)carve((size_t)B_ * 2 * S_ * 384 * 2);
  u16* AO  = (u16*)carve((size_t)BS_ * 1536 * 2);
  u16* PR  = (u16*)carve((size_t)BS_ * 1536 * 2);   // proj output (bf16)

  const float sReg = 0.08838834764831845f * L2E_;
  const float sCul = 0.05103103630798288f * L2E_;

  conv_x_k<<<dim3(BS_ * E_ / 4 / 256), 256, 0, stream>>>(x, Xb, BS_ * E_ / 4);
  bias_k<<<dim3(24), 256, 0, stream>>>(rq_b, rk_b, rv_b, cq_b, ck_b, cv_b,
                                       ro_b, co_b, r_cb, c_cb, bqkv, bproj);

  TP tp;
  const int wsel[6] = {0, 1, 2, 4, 5, 6};  // rq rk rv cq ck cv
  for (int i = 0; i < 6; ++i) {
    tp.src[i] = W[wsel[i]];
    tp.dst[i] = WqkvT + (size_t)i * 768 * 768;
    tp.rows[i] = 768;
  }
  tp.src[6] = W[3]; tp.dst[6] = roT;   tp.rows[6] = 768;   // ro_w
  tp.src[7] = W[7]; tp.dst[7] = coT;   tp.rows[7] = 768;   // co_w
  tp.src[8] = out_w; tp.dst[8] = outwT; tp.rows[8] = 1536; // out_w
  transpose_k<<<dim3(24, 48, 9), 256, 0, stream>>>(tp);

  // fused QKV projection, transposed: M=4608 features, N=4096 tokens
  gemm_t_k<2><<<dim3(32, 36), 256, 0, stream>>>(
      WqkvT, 768, Xb, 768, bqkv, 768,
      (const u16*)nullptr, 0, 0, (void*)nullptr, 0,
      Qr, Kr, Vtr, Qc, Kc, Vtc);

  // fused flash attention v3: 384 blocks, XCD-aware 1-D grid, KR=1
  attn_fused3_k<<<dim3(384), 256, 0, stream>>>(
      Qr, Kr, Vtr, Qc, Kc, Vtc, AO, amask, cmask, sReg, sCul);

  // merged per-branch output projections, transposed (m-split selects coT)
  gemm_t_k<0><<<dim3(32, 12), 256, 0, stream>>>(
      roT, 768, AO, 1536, bproj, 768,
      coT, 768, 768, (void*)PR, 1536,
      nullptr, nullptr, nullptr, nullptr, nullptr, nullptr);

  // final, transposed: M=768 out-features, N=4096 tokens -> fp32 float4 stores
  gemm_t_k<1><<<dim3(32, 6), 256, 0, stream>>>(
      outwT, 1536, PR, 1536, out_b, 1536,
      (const u16*)nullptr, 0, 0, d_out, 768,
      nullptr, nullptr, nullptr, nullptr, nullptr, nullptr);
}

// Round 4
// 462.745 us; speedup vs baseline: 1.9741x; 1.9741x over previous
//
#include <hip/hip_runtime.h>
#include <hip/hip_bf16.h>

using u16 = unsigned short;
using u32 = unsigned int;
typedef short short8 __attribute__((ext_vector_type(8)));
typedef float f32x4 __attribute__((ext_vector_type(4)));

#define B_  2
#define S_  2048
#define E_  768
#define BS_ 4096

#define L2E_ 1.44269504088896f
#define FML2_ 17.3123404906676f   // 12.0 * log2(e) fixed softmax stabilizer

__device__ __forceinline__ u16 f2bf(float f) {
  __hip_bfloat16 h = __float2bfloat16(f);
  return *reinterpret_cast<u16*>(&h);
}

__device__ __forceinline__ u32 pk2(float a, float b) {
  return (u32)f2bf(a) | ((u32)f2bf(b) << 16);
}

// async global->LDS, 16B per lane. LDS dest must be wave-uniform base + lane*16.
__device__ __forceinline__ void gld16(const void* g, void* l) {
  __builtin_amdgcn_global_load_lds(
      (const __attribute__((address_space(1))) u32*)g,
      (__attribute__((address_space(3))) u32*)l, 16, 0, 0);
}

// ---------------- fused preprocessing: conv-x | conv-weights | transposes |
// biases | fused output bias. One launch; block ranges select the task. ----------------
struct PrepP {
  const float* x;  u16* Xb;
  const float* row; const float* cow; u16* Wrc;   // [ro_w;co_w] -> bf16 straight
  const float* tsrc[7]; u16* tdst[7]; int trows[7];
  const float* rqb; const float* rkb; const float* rvb;
  const float* cqb; const float* ckb; const float* cvb;
  const float* rcb; const float* ccb;
  float* bqkv; float* bzero;
  const float* out_w; const float* out_b;
  const float* ro_b; const float* co_b; float* bfused;
};

__global__ __launch_bounds__(256) void prep_k(PrepP p) {
  const int bid = blockIdx.x, tid = threadIdx.x;
  __shared__ float tsh[32][33];
  if (bid < 3072) {                       // x -> Xb bf16 (786432 float4s)
    int i = bid * 256 + tid;
    float4 v = reinterpret_cast<const float4*>(p.x)[i];
    reinterpret_cast<uint2*>(p.Xb)[i] = make_uint2(pk2(v.x, v.y), pk2(v.z, v.w));
  } else if (bid < 4224) {                // [ro_w;co_w] -> Wrc bf16 (294912 f4)
    int i = (bid - 3072) * 256 + tid;
    const float* s = (i < 147456) ? p.row : p.cow;
    int k = (i < 147456) ? i : i - 147456;
    float4 v = reinterpret_cast<const float4*>(s)[k];
    reinterpret_cast<uint2*>(p.Wrc)[i] = make_uint2(pk2(v.x, v.y), pk2(v.z, v.w));
  } else if (bid < 8832) {                // transposes: 6x(24x24) + 1x(48x24)
    int tb = bid - 4224;
    int mi, ty, tx;
    if (tb < 3456) { mi = tb / 576; int r = tb - mi * 576; ty = r / 24; tx = r - ty * 24; }
    else           { int r = tb - 3456; mi = 6; ty = r / 24; tx = r - ty * 24; }
    const float* src = p.tsrc[mi];
    u16* dst = p.tdst[mi];
    const int rows = p.trows[mi];
    const int r0 = ty * 32, c0 = tx * 32;
    const int txx = tid & 31, tyy = tid >> 5;
#pragma unroll
    for (int d = 0; d < 4; ++d) {
      int r = tyy + d * 8;
      tsh[r][txx] = src[(size_t)(r0 + r) * 768 + c0 + txx];
    }
    __syncthreads();
#pragma unroll
    for (int d = 0; d < 4; ++d) {
      int c = tyy + d * 8;
      dst[(size_t)(c0 + c) * rows + r0 + txx] = f2bf(tsh[txx][c]);
    }
  } else if (bid < 8856) {                // bqkv + bzero
    int t = (bid - 8832) * 256 + tid;
    if (t < 4608) {
      int seg = t / 768, i = t - seg * 768;
      float v = 0.f;
      if      (seg == 0) v = p.rqb[i] + p.rcb[i];   // cultural bias folds into Q bias
      else if (seg == 1) v = p.rkb[i];
      else if (seg == 2) v = p.rvb[i];
      else if (seg == 3) v = p.cqb[i] + p.ccb[i];
      else if (seg == 4) v = p.ckb[i];
      else               v = p.cvb[i];
      p.bqkv[t] = v;
    } else if (t < 6144) {
      p.bzero[t - 4608] = 0.f;
    }
  } else {                                // bfused[of] = out_b + ro_b@Wtop + co_b@Wbot
    int of = (bid - 8856) * 256 + tid;    // 3 blocks -> of in [0,768)
    float acc = p.out_b[of];
#pragma unroll 4
    for (int m = 0; m < 768; ++m)
      acc = fmaf(p.ro_b[m], p.out_w[(size_t)m * 768 + of],
            fmaf(p.co_b[m], p.out_w[(size_t)(768 + m) * 768 + of], acc));
    p.bfused[of] = acc;
  }
}

// ============ transposed GEMM: computes C^T, i.e. C[row=M][col=N] with
// A[M][K], BT[N][K]; lane's 4 acc values are CONSECUTIVE M-rows -> packed
// 8B stores. MODE 0: PROJ (bf16 -> Cout[col*ldc+row], m-split A select)
// MODE 1: FINAL (fp32 float4 -> Cout[col*ldc+row])
// MODE 2: QKVT routing (M=feature, N=token) ============

template<int MODE>
__global__ __launch_bounds__(256) void gemm_t_k(
    const u16* __restrict__ A, int lda,
    const u16* __restrict__ BT, int ldb,
    const float* __restrict__ bias, int K,
    const u16* __restrict__ A2, int msplit, int bofs,
    void* __restrict__ Cout, int ldc,
    u16* __restrict__ Qr, u16* __restrict__ Kr, u16* __restrict__ Vtr,
    u16* __restrict__ Qc, u16* __restrict__ Kc, u16* __restrict__ Vtc) {
  __shared__ u16 lA[128 * 32];
  __shared__ u16 lB[128 * 32];
  const int tid = threadIdx.x, w = tid >> 6, lane = tid & 63;
  const int quad = lane >> 4, l15 = lane & 15;
  const int m0 = blockIdx.y * 128, n0 = blockIdx.x * 128;
  if (msplit && m0 >= msplit) { A = A2 - (size_t)msplit * lda; BT += bofs; }

  const f32x4 z4 = {0.f, 0.f, 0.f, 0.f};
  f32x4 acc[4][4];
#pragma unroll
  for (int i = 0; i < 4; ++i)
#pragma unroll
    for (int j = 0; j < 4; ++j) acc[i][j] = z4;

  const int sr = w * 32 + (lane >> 2);
  const int scp = lane & 3;

  for (int kt = 0; kt < K; kt += 32) {
    int r1 = sr, r2 = sr + 16;
    int c1 = (scp - (r1 >> 2)) & 3;
    int c2 = (scp - (r2 >> 2)) & 3;
    gld16(A + (size_t)(m0 + r1) * lda + kt + c1 * 8, &lA[r1 * 32 + scp * 8]);
    gld16(A + (size_t)(m0 + r2) * lda + kt + c2 * 8, &lA[r2 * 32 + scp * 8]);
    gld16(BT + (size_t)(n0 + r1) * ldb + kt + c1 * 8, &lB[r1 * 32 + scp * 8]);
    gld16(BT + (size_t)(n0 + r2) * ldb + kt + c2 * 8, &lB[r2 * 32 + scp * 8]);
    __syncthreads();
    short8 af[4], bg[4];
#pragma unroll
    for (int i = 0; i < 4; ++i) {
      int r = (w >> 1) * 64 + i * 16 + l15;
      af[i] = *reinterpret_cast<const short8*>(&lA[r * 32 + ((quad + (r >> 2)) & 3) * 8]);
    }
#pragma unroll
    for (int j = 0; j < 4; ++j) {
      int r = (w & 1) * 64 + j * 16 + l15;
      bg[j] = *reinterpret_cast<const short8*>(&lB[r * 32 + ((quad + (r >> 2)) & 3) * 8]);
    }
#pragma unroll
    for (int i = 0; i < 4; ++i)
#pragma unroll
      for (int j = 0; j < 4; ++j)
        acc[i][j] = __builtin_amdgcn_mfma_f32_16x16x32_bf16(af[i], bg[j], acc[i][j], 0, 0, 0);
    __syncthreads();
  }

  const int seg = (MODE == 2) ? (m0 / 768) : 0;
#pragma unroll
  for (int i = 0; i < 4; ++i) {
    int f = m0 + (w >> 1) * 64 + i * 16 + quad * 4;   // M-row base (4 consecutive)
    float4 b4 = *reinterpret_cast<const float4*>(bias + f);
#pragma unroll
    for (int j = 0; j < 4; ++j) {
      int t = n0 + (w & 1) * 64 + j * 16 + l15;        // N-col
      float v0 = acc[i][j][0] + b4.x;
      float v1 = acc[i][j][1] + b4.y;
      float v2 = acc[i][j][2] + b4.z;
      float v3 = acc[i][j][3] + b4.w;
      if (MODE == 0) {
        *reinterpret_cast<uint2*>((u16*)Cout + (size_t)t * ldc + f) =
            make_uint2(pk2(v0, v1), pk2(v2, v3));
      } else if (MODE == 1) {
        *reinterpret_cast<float4*>((float*)Cout + (size_t)t * ldc + f) =
            make_float4(v0, v1, v2, v3);
      } else {
        int b = t >> 11, s = t & 2047;
        int fs = f - seg * 768;
        if (seg == 0) {
          int h = fs >> 7, d = fs & 127;
          *reinterpret_cast<uint2*>(Qr + ((size_t)(b * 6 + h) * 2048 + s) * 128 + d) =
              make_uint2(pk2(v0, v1), pk2(v2, v3));
        } else if (seg == 1) {
          int h = fs >> 7, d = fs & 127;
          *reinterpret_cast<uint2*>(Kr + ((size_t)(b * 6 + h) * 2048 + s) * 128 + d) =
              make_uint2(pk2(v0, v1), pk2(v2, v3));
        } else if (seg == 2) {
          int h = fs >> 7, d = fs & 127;
          u16* vp = Vtr + ((size_t)(b * 6 + h) * 128 + d) * 2048 + s;
          vp[0] = f2bf(v0); vp[2048] = f2bf(v1); vp[4096] = f2bf(v2); vp[6144] = f2bf(v3);
        } else if (seg == 3) {
          int h = fs / 384, d = fs - h * 384;
          *reinterpret_cast<uint2*>(Qc + ((size_t)(b * 2 + h) * 2048 + s) * 384 + d) =
              make_uint2(pk2(v0, v1), pk2(v2, v3));
        } else if (seg == 4) {
          int h = fs / 384, d = fs - h * 384;
          *reinterpret_cast<uint2*>(Kc + ((size_t)(b * 2 + h) * 2048 + s) * 384 + d) =
              make_uint2(pk2(v0, v1), pk2(v2, v3));
        } else {
          int h = fs / 384, d = fs - h * 384;
          u16* vp = Vtc + ((size_t)(b * 2 + h) * 384 + d) * 2048 + s;
          vp[0] = f2bf(v0); vp[2048] = f2bf(v1); vp[4096] = f2bf(v2); vp[6144] = f2bf(v3);
        }
      }
    }
  }
}

// ---------------- attention g1 (transposed): S^T[k][q] = K·Q^T ----------------
// A = K-matrix (M=keys), BT = Q-matrix (N=queries); lane's 4 values are
// consecutive KEYS -> P[q][k] written as packed uint2; cm/am as float4 loads.
// Row-sums over keys: 2 shfl_xor + 32-partial Lp[gz][32][S].
__global__ __launch_bounds__(256) void attn_g1_k(
    const u16* __restrict__ Qr, const u16* __restrict__ Kr,
    const u16* __restrict__ Qc, const u16* __restrict__ Kc,
    u16* __restrict__ Pr, u16* __restrict__ Pc, float* __restrict__ Lp,
    const float* __restrict__ am, const float* __restrict__ cmask,
    float sReg, float sCul, int zoff) {
  __shared__ u16 lA[128 * 32];
  __shared__ u16 lB[128 * 32];
  const int tid = threadIdx.x, w = tid >> 6, lane = tid & 63;
  const int quad = lane >> 4, l15 = lane & 15;
  const int m0 = blockIdx.y * 128, n0 = blockIdx.x * 128;  // m=key, n=query
  const int gz = zoff + blockIdx.z;
  const u16 *A, *BT;
  u16* P;
  const float* cm = nullptr;
  float scl;
  int K, b;
  if (gz < 12) {
    A = Kr + (size_t)gz * S_ * 128;
    BT = Qr + (size_t)gz * S_ * 128;
    K = 128;
    P = Pr + (size_t)blockIdx.z * (size_t)S_ * S_;
    scl = sReg;
    b = gz / 6;
  } else {
    int hc = gz - 12;
    A = Kc + (size_t)hc * S_ * 384;
    BT = Qc + (size_t)hc * S_ * 384;
    K = 384;
    P = Pc + (size_t)hc * (size_t)S_ * S_;
    b = hc >> 1;
    cm = cmask + (size_t)b * S_ * S_;
    scl = sCul;
  }

  const f32x4 z4 = {0.f, 0.f, 0.f, 0.f};
  f32x4 acc[4][4];
#pragma unroll
  for (int i = 0; i < 4; ++i)
#pragma unroll
    for (int j = 0; j < 4; ++j) acc[i][j] = z4;

  const int sr = w * 32 + (lane >> 2);
  const int scp = lane & 3;

  for (int kt = 0; kt < K; kt += 32) {
    int r1 = sr, r2 = sr + 16;
    int c1 = (scp - (r1 >> 2)) & 3;
    int c2 = (scp - (r2 >> 2)) & 3;
    gld16(A + (size_t)(m0 + r1) * K + kt + c1 * 8, &lA[r1 * 32 + scp * 8]);
    gld16(A + (size_t)(m0 + r2) * K + kt + c2 * 8, &lA[r2 * 32 + scp * 8]);
    gld16(BT + (size_t)(n0 + r1) * K + kt + c1 * 8, &lB[r1 * 32 + scp * 8]);
    gld16(BT + (size_t)(n0 + r2) * K + kt + c2 * 8, &lB[r2 * 32 + scp * 8]);
    __syncthreads();
    short8 af[4], bg[4];
#pragma unroll
    for (int i = 0; i < 4; ++i) {
      int r = (w >> 1) * 64 + i * 16 + l15;
      af[i] = *reinterpret_cast<const short8*>(&lA[r * 32 + ((quad + (r >> 2)) & 3) * 8]);
    }
#pragma unroll
    for (int j = 0; j < 4; ++j) {
      int r = (w & 1) * 64 + j * 16 + l15;
      bg[j] = *reinterpret_cast<const short8*>(&lB[r * 32 + ((quad + (r >> 2)) & 3) * 8]);
    }
#pragma unroll
    for (int i = 0; i < 4; ++i)
#pragma unroll
      for (int j = 0; j < 4; ++j)
        acc[i][j] = __builtin_amdgcn_mfma_f32_16x16x32_bf16(af[i], bg[j], acc[i][j], 0, 0, 0);
    __syncthreads();
  }

  // epilogue: p = exp2(acc*scl + am[k]*l2e (+ cm[q][k]*l2e) - M), packed stores
  const float* amb = am + b * S_;
  float lsum[4] = {0.f, 0.f, 0.f, 0.f};
#pragma unroll
  for (int i = 0; i < 4; ++i) {
    int kb = m0 + (w >> 1) * 64 + i * 16 + quad * 4;    // 4 consecutive keys
    float4 a4 = *reinterpret_cast<const float4*>(amb + kb);
    float pre0 = fmaf(a4.x, L2E_, -FML2_);
    float pre1 = fmaf(a4.y, L2E_, -FML2_);
    float pre2 = fmaf(a4.z, L2E_, -FML2_);
    float pre3 = fmaf(a4.w, L2E_, -FML2_);
#pragma unroll
    for (int j = 0; j < 4; ++j) {
      int q = n0 + (w & 1) * 64 + j * 16 + l15;
      float c0 = pre0, c1 = pre1, c2 = pre2, c3 = pre3;
      if (cm) {
        float4 cmv = *reinterpret_cast<const float4*>(cm + (size_t)q * S_ + kb);
        c0 = fmaf(cmv.x, L2E_, c0);
        c1 = fmaf(cmv.y, L2E_, c1);
        c2 = fmaf(cmv.z, L2E_, c2);
        c3 = fmaf(cmv.w, L2E_, c3);
      }
      float p0 = exp2f(fmaf(acc[i][j][0], scl, c0));
      float p1 = exp2f(fmaf(acc[i][j][1], scl, c1));
      float p2 = exp2f(fmaf(acc[i][j][2], scl, c2));
      float p3 = exp2f(fmaf(acc[i][j][3], scl, c3));
      lsum[j] += (p0 + p1) + (p2 + p3);
      *reinterpret_cast<uint2*>(P + (size_t)q * S_ + kb) =
          make_uint2(pk2(p0, p1), pk2(p2, p3));
    }
  }
#pragma unroll
  for (int j = 0; j < 4; ++j) {
    float s = lsum[j];
    s += __shfl_xor(s, 16);
    s += __shfl_xor(s, 32);
    if (lane < 16)
      Lp[(size_t)gz * (32 * S_) + ((size_t)((m0 >> 7) * 2 + (w >> 1))) * S_ +
         n0 + (w & 1) * 64 + j * 16 + lane] = s;
  }
}

// ---------------- attention g2 (transposed): O^T[d][q] = Vt·P^T ----------------
// A = Vt (M=HD), BT = P[q][k] natural (N=queries), K = S_. Normalize by 1/l[q],
// write packed uint2 into AO[token][feature] (4 consecutive features).
__global__ __launch_bounds__(256) void attn_g2_k(
    const u16* __restrict__ Pr, const u16* __restrict__ Pc,
    const u16* __restrict__ Vtr, const u16* __restrict__ Vtc,
    const float* __restrict__ Lp, u16* __restrict__ AO, int zoff) {
  const int gz = zoff + blockIdx.z;
  const int m0 = blockIdx.y * 128, n0 = blockIdx.x * 128;  // m=feat, n=query
  const u16 *A, *BT;
  int b, colbase;
  if (gz < 12) {
    if (blockIdx.y) return;  // M = 128
    A = Vtr + (size_t)gz * 128 * S_;
    BT = Pr + (size_t)blockIdx.z * (size_t)S_ * S_;
    b = gz / 6;
    colbase = (gz % 6) * 128;
  } else {
    int hc = gz - 12;
    A = Vtc + (size_t)hc * 384 * S_;
    BT = Pc + (size_t)hc * (size_t)S_ * S_;
    b = hc >> 1;
    colbase = 768 + (hc & 1) * 384;
  }
  __shared__ u16 lA[128 * 32];
  __shared__ u16 lB[128 * 32];
  __shared__ float lL[128];
  const int tid = threadIdx.x, w = tid >> 6, lane = tid & 63;
  const int quad = lane >> 4, l15 = lane & 15;

  if (tid < 128) {
    const float* lp = Lp + (size_t)gz * (32 * S_) + (n0 + tid);
    float s = 0.f;
#pragma unroll
    for (int g = 0; g < 32; ++g) s += lp[(size_t)g * S_];
    lL[tid] = 1.f / s;
  }

  const f32x4 z4 = {0.f, 0.f, 0.f, 0.f};
  f32x4 acc[4][4];
#pragma unroll
  for (int i = 0; i < 4; ++i)
#pragma unroll
    for (int j = 0; j < 4; ++j) acc[i][j] = z4;

  const int sr = w * 32 + (lane >> 2);
  const int scp = lane & 3;

  for (int kt = 0; kt < S_; kt += 32) {
    int r1 = sr, r2 = sr + 16;
    int c1 = (scp - (r1 >> 2)) & 3;
    int c2 = (scp - (r2 >> 2)) & 3;
    gld16(A + (size_t)(m0 + r1) * S_ + kt + c1 * 8, &lA[r1 * 32 + scp * 8]);
    gld16(A + (size_t)(m0 + r2) * S_ + kt + c2 * 8, &lA[r2 * 32 + scp * 8]);
    gld16(BT + (size_t)(n0 + r1) * S_ + kt + c1 * 8, &lB[r1 * 32 + scp * 8]);
    gld16(BT + (size_t)(n0 + r2) * S_ + kt + c2 * 8, &lB[r2 * 32 + scp * 8]);
    __syncthreads();
    short8 af[4], bg[4];
#pragma unroll
    for (int i = 0; i < 4; ++i) {
      int r = (w >> 1) * 64 + i * 16 + l15;
      af[i] = *reinterpret_cast<const short8*>(&lA[r * 32 + ((quad + (r >> 2)) & 3) * 8]);
    }
#pragma unroll
    for (int j = 0; j < 4; ++j) {
      int r = (w & 1) * 64 + j * 16 + l15;
      bg[j] = *reinterpret_cast<const short8*>(&lB[r * 32 + ((quad + (r >> 2)) & 3) * 8]);
    }
#pragma unroll
    for (int i = 0; i < 4; ++i)
#pragma unroll
      for (int j = 0; j < 4; ++j)
        acc[i][j] = __builtin_amdgcn_mfma_f32_16x16x32_bf16(af[i], bg[j], acc[i][j], 0, 0, 0);
    __syncthreads();
  }

  float invl[4];
#pragma unroll
  for (int j = 0; j < 4; ++j) invl[j] = lL[(w & 1) * 64 + j * 16 + l15];
#pragma unroll
  for (int i = 0; i < 4; ++i) {
    int feat = colbase + m0 + (w >> 1) * 64 + i * 16 + quad * 4;
#pragma unroll
    for (int j = 0; j < 4; ++j) {
      int q = n0 + (w & 1) * 64 + j * 16 + l15;
      float v0 = acc[i][j][0] * invl[j];
      float v1 = acc[i][j][1] * invl[j];
      float v2 = acc[i][j][2] * invl[j];
      float v3 = acc[i][j][3] * invl[j];
      *reinterpret_cast<uint2*>(AO + ((size_t)(b * S_ + q)) * 1536 + feat) =
          make_uint2(pk2(v0, v1), pk2(v2, v3));
    }
  }
}

// ---------------- launcher ----------------

extern "C" void kernel_launch(void* const* d_in, const int* in_sizes, int n_in,
                              void* d_out, int out_size, void* d_ws, size_t ws_size,
                              hipStream_t stream) {
  const float* x     = (const float*)d_in[0];
  const float* cmask = (const float*)d_in[1];
  const float* amask = (const float*)d_in[2];
  const float* W[8]  = { (const float*)d_in[3], (const float*)d_in[4], (const float*)d_in[5],
                         (const float*)d_in[6], (const float*)d_in[7], (const float*)d_in[8],
                         (const float*)d_in[9], (const float*)d_in[10] };
  const float* rq_b = (const float*)d_in[11];
  const float* rk_b = (const float*)d_in[12];
  const float* rv_b = (const float*)d_in[13];
  const float* ro_b = (const float*)d_in[14];
  const float* cq_b = (const float*)d_in[15];
  const float* ck_b = (const float*)d_in[16];
  const float* cv_b = (const float*)d_in[17];
  const float* co_b = (const float*)d_in[18];
  const float* r_cb = (const float*)d_in[19];
  const float* c_cb = (const float*)d_in[20];
  const float* out_w = (const float*)d_in[21];
  const float* out_b = (const float*)d_in[22];

  char* p = (char*)d_ws;
  auto carve = [&](size_t bytes) -> void* {
    void* r = (void*)p;
    p += (bytes + 255) & ~(size_t)255;
    return r;
  };
  u16* Xb    = (u16*)carve((size_t)BS_ * E_ * 2);       // dead after QKV gemm
  u16* WqkvT = (u16*)carve((size_t)4608 * 768 * 2);     // dead after QKV gemm
  u16* outwT = (u16*)carve((size_t)768 * 1536 * 2);
  u16* Wrc   = (u16*)carve((size_t)1536 * 768 * 2);     // [ro_w;co_w] bf16 straight
  u16* WfT   = (u16*)carve((size_t)768 * 1536 * 2);     // fused proj weight
  float* bqkv   = (float*)carve(4608 * 4);
  float* bzero  = (float*)carve(1536 * 4);
  float* bfused = (float*)carve(768 * 4);
  u16* Qr  = (u16*)carve((size_t)B_ * 6 * S_ * 128 * 2);
  u16* Kr  = (u16*)carve((size_t)B_ * 6 * S_ * 128 * 2);
  u16* Vtr = (u16*)carve((size_t)B_ * 6 * S_ * 128 * 2);
  u16* Qc  = (u16*)carve((size_t)B_ * 2 * S_ * 384 * 2);
  u16* Kc  = (u16*)carve((size_t)B_ * 2 * S_ * 384 * 2);
  u16* Vtc = (u16*)carve((size_t)B_ * 2 * S_ * 384 * 2);
  u16* AO  = (u16*)carve((size_t)BS_ * 1536 * 2);

  // Lp aliases dead Xb region (4.2 MB <= 6.3 MB).
  float* Lp = (float*)Xb;
  u16* Pcul = (u16*)carve((size_t)4 * S_ * S_ * 2);     // 33.6 MB
  size_t used = (size_t)(p - (char*)d_ws);
  size_t rem = (ws_size > used) ? (ws_size - used) : 0;
  int RCH;                                              // regular heads per chunk
  if      (rem >= (size_t)12 * S_ * S_ * 2 + 4096) RCH = 12;
  else if (rem >= (size_t)4  * S_ * S_ * 2 + 4096) RCH = 4;
  else                                             RCH = 2;
  u16* Preg = (u16*)carve((size_t)RCH * S_ * S_ * 2);

  const float sReg = 0.08838834764831845f * L2E_;
  const float sCul = 0.05103103630798288f * L2E_;

  // ---- single preprocessing launch ----
  PrepP pp;
  pp.x = x; pp.Xb = Xb;
  pp.row = W[3]; pp.cow = W[7]; pp.Wrc = Wrc;
  const int wsel[6] = {0, 1, 2, 4, 5, 6};  // rq rk rv cq ck cv
  for (int i = 0; i < 6; ++i) {
    pp.tsrc[i] = W[wsel[i]];
    pp.tdst[i] = WqkvT + (size_t)i * 768 * 768;
    pp.trows[i] = 768;
  }
  pp.tsrc[6] = out_w; pp.tdst[6] = outwT; pp.trows[6] = 1536;
  pp.rqb = rq_b; pp.rkb = rk_b; pp.rvb = rv_b;
  pp.cqb = cq_b; pp.ckb = ck_b; pp.cvb = cv_b;
  pp.rcb = r_cb; pp.ccb = c_cb;
  pp.bqkv = bqkv; pp.bzero = bzero;
  pp.out_w = out_w; pp.out_b = out_b;
  pp.ro_b = ro_b; pp.co_b = co_b; pp.bfused = bfused;
  prep_k<<<dim3(8859), 256, 0, stream>>>(pp);

  // ---- fused projection weight: WfT[of][if] = sum_m Wrc[if][m] * out_w[m + sel*768][of]
  // M=if(1536), N=of(768), K=768; msplit trick keeps A=Wrc, shifts outwT cols by 768.
  gemm_t_k<0><<<dim3(6, 12), 256, 0, stream>>>(
      Wrc, 768, outwT, 1536, bzero, 768,
      Wrc + (size_t)768 * 768, 768, 768, (void*)WfT, 1536,
      nullptr, nullptr, nullptr, nullptr, nullptr, nullptr);

  // fused QKV projection, transposed: M=4608 features, N=4096 tokens
  gemm_t_k<2><<<dim3(32, 36), 256, 0, stream>>>(
      WqkvT, 768, Xb, 768, bqkv, 768,
      (const u16*)nullptr, 0, 0, (void*)nullptr, 0,
      Qr, Kr, Vtr, Qc, Kc, Vtc);

  if (RCH == 12) {
    attn_g1_k<<<dim3(16, 16, 16), 256, 0, stream>>>(
        Qr, Kr, Qc, Kc, Preg, Pcul, Lp, amask, cmask, sReg, sCul, 0);
    attn_g2_k<<<dim3(16, 3, 16), 256, 0, stream>>>(
        Preg, Pcul, Vtr, Vtc, Lp, AO, 0);
  } else {
    attn_g1_k<<<dim3(16, 16, 4), 256, 0, stream>>>(
        Qr, Kr, Qc, Kc, Preg, Pcul, Lp, amask, cmask, sReg, sCul, 12);
    attn_g2_k<<<dim3(16, 3, 4), 256, 0, stream>>>(
        Preg, Pcul, Vtr, Vtc, Lp, AO, 12);
    for (int c = 0; c < 12; c += RCH) {
      attn_g1_k<<<dim3(16, 16, RCH), 256, 0, stream>>>(
          Qr, Kr, Qc, Kc, Preg, Pcul, Lp, amask, cmask, sReg, sCul, c);
      attn_g2_k<<<dim3(16, 1, RCH), 256, 0, stream>>>(
          Preg, Pcul, Vtr, Vtc, Lp, AO, c);
    }
  }

  // final fused projection: M=768 out-features, N=4096 tokens, K=1536
  gemm_t_k<1><<<dim3(32, 6), 256, 0, stream>>>(
      WfT, 1536, AO, 1536, bfused, 1536,
      (const u16*)nullptr, 0, 0, d_out, 768,
      nullptr, nullptr, nullptr, nullptr, nullptr, nullptr);
}

// Round 5
// 425.031 us; speedup vs baseline: 2.1493x; 1.0887x over previous
//
#include <hip/hip_runtime.h>
#include <hip/hip_bf16.h>

using u16 = unsigned short;
using u32 = unsigned int;
typedef short short8 __attribute__((ext_vector_type(8)));
typedef float f32x4 __attribute__((ext_vector_type(4)));

#define B_  2
#define S_  2048
#define E_  768
#define BS_ 4096

#define L2E_ 1.44269504088896f
#define FML2_ 17.3123404906676f   // 12.0 * log2(e) fixed softmax stabilizer

__device__ __forceinline__ u16 f2bf(float f) {
  __hip_bfloat16 h = __float2bfloat16(f);
  return *reinterpret_cast<u16*>(&h);
}

__device__ __forceinline__ u32 pk2(float a, float b) {
  return (u32)f2bf(a) | ((u32)f2bf(b) << 16);
}

// async global->LDS, 16B per lane. LDS dest must be wave-uniform base + lane*16.
__device__ __forceinline__ void gld16(const void* g, void* l) {
  __builtin_amdgcn_global_load_lds(
      (const __attribute__((address_space(1))) u32*)g,
      (__attribute__((address_space(3))) u32*)l, 16, 0, 0);
}

// ---------------- fused preprocessing: conv-x | conv-weights | transposes |
// biases. One launch; block ranges select the task. ----------------
struct PrepP {
  const float* x;  u16* Xb;
  const float* row; const float* cow; u16* Wrc;   // [ro_w;co_w] -> bf16 straight
  const float* tsrc[7]; u16* tdst[7]; int trows[7];
  const float* rqb; const float* rkb; const float* rvb;
  const float* cqb; const float* ckb; const float* cvb;
  const float* rcb; const float* ccb;
  float* bqkv; float* bzero;
};

__global__ __launch_bounds__(256) void prep_k(PrepP p) {
  const int bid = blockIdx.x, tid = threadIdx.x;
  __shared__ float tsh[32][33];
  if (bid < 3072) {                       // x -> Xb bf16 (786432 float4s)
    int i = bid * 256 + tid;
    float4 v = reinterpret_cast<const float4*>(p.x)[i];
    reinterpret_cast<uint2*>(p.Xb)[i] = make_uint2(pk2(v.x, v.y), pk2(v.z, v.w));
  } else if (bid < 4224) {                // [ro_w;co_w] -> Wrc bf16 (294912 f4)
    int i = (bid - 3072) * 256 + tid;
    const float* s = (i < 147456) ? p.row : p.cow;
    int k = (i < 147456) ? i : i - 147456;
    float4 v = reinterpret_cast<const float4*>(s)[k];
    reinterpret_cast<uint2*>(p.Wrc)[i] = make_uint2(pk2(v.x, v.y), pk2(v.z, v.w));
  } else if (bid < 8832) {                // transposes: 6x(24x24) + 1x(48x24)
    int tb = bid - 4224;
    int mi, ty, tx;
    if (tb < 3456) { mi = tb / 576; int r = tb - mi * 576; ty = r / 24; tx = r - ty * 24; }
    else           { int r = tb - 3456; mi = 6; ty = r / 24; tx = r - ty * 24; }
    const float* src = p.tsrc[mi];
    u16* dst = p.tdst[mi];
    const int rows = p.trows[mi];
    const int r0 = ty * 32, c0 = tx * 32;
    const int txx = tid & 31, tyy = tid >> 5;
#pragma unroll
    for (int d = 0; d < 4; ++d) {
      int r = tyy + d * 8;
      tsh[r][txx] = src[(size_t)(r0 + r) * 768 + c0 + txx];
    }
    __syncthreads();
#pragma unroll
    for (int d = 0; d < 4; ++d) {
      int c = tyy + d * 8;
      dst[(size_t)(c0 + c) * rows + r0 + txx] = f2bf(tsh[txx][c]);
    }
  } else {                                // bqkv + bzero (24 blocks)
    int t = (bid - 8832) * 256 + tid;
    if (t < 4608) {
      int seg = t / 768, i = t - seg * 768;
      float v = 0.f;
      if      (seg == 0) v = p.rqb[i] + p.rcb[i];   // cultural bias folds into Q bias
      else if (seg == 1) v = p.rkb[i];
      else if (seg == 2) v = p.rvb[i];
      else if (seg == 3) v = p.cqb[i] + p.ccb[i];
      else if (seg == 4) v = p.ckb[i];
      else               v = p.cvb[i];
      p.bqkv[t] = v;
    } else if (t < 6144) {
      p.bzero[t - 4608] = 0.f;
    }
  }
}

// bfused[of] = out_b[of] + sum_m [ro_b;co_b][m] * out_w[m][of], via outwT rows
// (contiguous bf16 per thread -> bandwidth-friendly; 3 blocks, ~2 us).
__global__ __launch_bounds__(256) void bfused_k(
    const u16* __restrict__ outwT, const float* __restrict__ out_b,
    const float* __restrict__ ro_b, const float* __restrict__ co_b,
    float* __restrict__ bfused) {
  __shared__ float rcb[1536];
  const int tid = threadIdx.x;
  for (int i = tid; i < 768; i += 256) {
    rcb[i] = ro_b[i];
    rcb[768 + i] = co_b[i];
  }
  __syncthreads();
  const int of = blockIdx.x * 256 + tid;            // grid 3 -> of in [0,768)
  const u16* row = outwT + (size_t)of * 1536;
  float a0 = out_b[of], a1 = 0.f, a2 = 0.f, a3 = 0.f;
  for (int m = 0; m < 1536; m += 8) {
    short8 v = *reinterpret_cast<const short8*>(row + m);
    u32 b0 = ((u32)(u16)v[0]) << 16, b1 = ((u32)(u16)v[1]) << 16;
    u32 b2 = ((u32)(u16)v[2]) << 16, b3 = ((u32)(u16)v[3]) << 16;
    u32 b4 = ((u32)(u16)v[4]) << 16, b5 = ((u32)(u16)v[5]) << 16;
    u32 b6 = ((u32)(u16)v[6]) << 16, b7 = ((u32)(u16)v[7]) << 16;
    a0 = fmaf(*reinterpret_cast<float*>(&b0), rcb[m + 0], a0);
    a1 = fmaf(*reinterpret_cast<float*>(&b1), rcb[m + 1], a1);
    a2 = fmaf(*reinterpret_cast<float*>(&b2), rcb[m + 2], a2);
    a3 = fmaf(*reinterpret_cast<float*>(&b3), rcb[m + 3], a3);
    a0 = fmaf(*reinterpret_cast<float*>(&b4), rcb[m + 4], a0);
    a1 = fmaf(*reinterpret_cast<float*>(&b5), rcb[m + 5], a1);
    a2 = fmaf(*reinterpret_cast<float*>(&b6), rcb[m + 6], a2);
    a3 = fmaf(*reinterpret_cast<float*>(&b7), rcb[m + 7], a3);
  }
  bfused[of] = (a0 + a1) + (a2 + a3);
}

// ============ transposed GEMM: computes C^T, i.e. C[row=M][col=N] with
// A[M][K], BT[N][K]; lane's 4 acc values are CONSECUTIVE M-rows -> packed
// 8B stores. MODE 0: PROJ (bf16 -> Cout[col*ldc+row], m-split A select)
// MODE 1: FINAL (fp32 float4 -> Cout[col*ldc+row])
// MODE 2: QKVT routing (M=feature, N=token) ============

template<int MODE>
__global__ __launch_bounds__(256) void gemm_t_k(
    const u16* __restrict__ A, int lda,
    const u16* __restrict__ BT, int ldb,
    const float* __restrict__ bias, int K,
    const u16* __restrict__ A2, int msplit, int bofs,
    void* __restrict__ Cout, int ldc,
    u16* __restrict__ Qr, u16* __restrict__ Kr, u16* __restrict__ Vtr,
    u16* __restrict__ Qc, u16* __restrict__ Kc, u16* __restrict__ Vtc) {
  __shared__ u16 lA[128 * 32];
  __shared__ u16 lB[128 * 32];
  const int tid = threadIdx.x, w = tid >> 6, lane = tid & 63;
  const int quad = lane >> 4, l15 = lane & 15;
  const int m0 = blockIdx.y * 128, n0 = blockIdx.x * 128;
  if (msplit && m0 >= msplit) { A = A2 - (size_t)msplit * lda; BT += bofs; }

  const f32x4 z4 = {0.f, 0.f, 0.f, 0.f};
  f32x4 acc[4][4];
#pragma unroll
  for (int i = 0; i < 4; ++i)
#pragma unroll
    for (int j = 0; j < 4; ++j) acc[i][j] = z4;

  const int sr = w * 32 + (lane >> 2);
  const int scp = lane & 3;

  for (int kt = 0; kt < K; kt += 32) {
    int r1 = sr, r2 = sr + 16;
    int c1 = (scp - (r1 >> 2)) & 3;
    int c2 = (scp - (r2 >> 2)) & 3;
    gld16(A + (size_t)(m0 + r1) * lda + kt + c1 * 8, &lA[r1 * 32 + scp * 8]);
    gld16(A + (size_t)(m0 + r2) * lda + kt + c2 * 8, &lA[r2 * 32 + scp * 8]);
    gld16(BT + (size_t)(n0 + r1) * ldb + kt + c1 * 8, &lB[r1 * 32 + scp * 8]);
    gld16(BT + (size_t)(n0 + r2) * ldb + kt + c2 * 8, &lB[r2 * 32 + scp * 8]);
    __syncthreads();
    short8 af[4], bg[4];
#pragma unroll
    for (int i = 0; i < 4; ++i) {
      int r = (w >> 1) * 64 + i * 16 + l15;
      af[i] = *reinterpret_cast<const short8*>(&lA[r * 32 + ((quad + (r >> 2)) & 3) * 8]);
    }
#pragma unroll
    for (int j = 0; j < 4; ++j) {
      int r = (w & 1) * 64 + j * 16 + l15;
      bg[j] = *reinterpret_cast<const short8*>(&lB[r * 32 + ((quad + (r >> 2)) & 3) * 8]);
    }
#pragma unroll
    for (int i = 0; i < 4; ++i)
#pragma unroll
      for (int j = 0; j < 4; ++j)
        acc[i][j] = __builtin_amdgcn_mfma_f32_16x16x32_bf16(af[i], bg[j], acc[i][j], 0, 0, 0);
    __syncthreads();
  }

  const int seg = (MODE == 2) ? (m0 / 768) : 0;
#pragma unroll
  for (int i = 0; i < 4; ++i) {
    int f = m0 + (w >> 1) * 64 + i * 16 + quad * 4;   // M-row base (4 consecutive)
    float4 b4 = *reinterpret_cast<const float4*>(bias + f);
#pragma unroll
    for (int j = 0; j < 4; ++j) {
      int t = n0 + (w & 1) * 64 + j * 16 + l15;        // N-col
      float v0 = acc[i][j][0] + b4.x;
      float v1 = acc[i][j][1] + b4.y;
      float v2 = acc[i][j][2] + b4.z;
      float v3 = acc[i][j][3] + b4.w;
      if (MODE == 0) {
        *reinterpret_cast<uint2*>((u16*)Cout + (size_t)t * ldc + f) =
            make_uint2(pk2(v0, v1), pk2(v2, v3));
      } else if (MODE == 1) {
        *reinterpret_cast<float4*>((float*)Cout + (size_t)t * ldc + f) =
            make_float4(v0, v1, v2, v3);
      } else {
        int b = t >> 11, s = t & 2047;
        int fs = f - seg * 768;
        if (seg == 0) {
          int h = fs >> 7, d = fs & 127;
          *reinterpret_cast<uint2*>(Qr + ((size_t)(b * 6 + h) * 2048 + s) * 128 + d) =
              make_uint2(pk2(v0, v1), pk2(v2, v3));
        } else if (seg == 1) {
          int h = fs >> 7, d = fs & 127;
          *reinterpret_cast<uint2*>(Kr + ((size_t)(b * 6 + h) * 2048 + s) * 128 + d) =
              make_uint2(pk2(v0, v1), pk2(v2, v3));
        } else if (seg == 2) {
          int h = fs >> 7, d = fs & 127;
          u16* vp = Vtr + ((size_t)(b * 6 + h) * 128 + d) * 2048 + s;
          vp[0] = f2bf(v0); vp[2048] = f2bf(v1); vp[4096] = f2bf(v2); vp[6144] = f2bf(v3);
        } else if (seg == 3) {
          int h = fs / 384, d = fs - h * 384;
          *reinterpret_cast<uint2*>(Qc + ((size_t)(b * 2 + h) * 2048 + s) * 384 + d) =
              make_uint2(pk2(v0, v1), pk2(v2, v3));
        } else if (seg == 4) {
          int h = fs / 384, d = fs - h * 384;
          *reinterpret_cast<uint2*>(Kc + ((size_t)(b * 2 + h) * 2048 + s) * 384 + d) =
              make_uint2(pk2(v0, v1), pk2(v2, v3));
        } else {
          int h = fs / 384, d = fs - h * 384;
          u16* vp = Vtc + ((size_t)(b * 2 + h) * 384 + d) * 2048 + s;
          vp[0] = f2bf(v0); vp[2048] = f2bf(v1); vp[4096] = f2bf(v2); vp[6144] = f2bf(v3);
        }
      }
    }
  }
}

// ---------------- attention g1 (transposed): S^T[k][q] = K·Q^T ----------------
// A = K-matrix (M=keys), BT = Q-matrix (N=queries); lane's 4 values are
// consecutive KEYS -> P[q][k] written as packed uint2; cm/am as float4 loads.
// Row-sums over keys: 2 shfl_xor + 32-partial Lp[gz][32][S].
__global__ __launch_bounds__(256) void attn_g1_k(
    const u16* __restrict__ Qr, const u16* __restrict__ Kr,
    const u16* __restrict__ Qc, const u16* __restrict__ Kc,
    u16* __restrict__ Pr, u16* __restrict__ Pc, float* __restrict__ Lp,
    const float* __restrict__ am, const float* __restrict__ cmask,
    float sReg, float sCul, int zoff) {
  __shared__ u16 lA[128 * 32];
  __shared__ u16 lB[128 * 32];
  const int tid = threadIdx.x, w = tid >> 6, lane = tid & 63;
  const int quad = lane >> 4, l15 = lane & 15;
  const int m0 = blockIdx.y * 128, n0 = blockIdx.x * 128;  // m=key, n=query
  const int gz = zoff + blockIdx.z;
  const u16 *A, *BT;
  u16* P;
  const float* cm = nullptr;
  float scl;
  int K, b;
  if (gz < 12) {
    A = Kr + (size_t)gz * S_ * 128;
    BT = Qr + (size_t)gz * S_ * 128;
    K = 128;
    P = Pr + (size_t)blockIdx.z * (size_t)S_ * S_;
    scl = sReg;
    b = gz / 6;
  } else {
    int hc = gz - 12;
    A = Kc + (size_t)hc * S_ * 384;
    BT = Qc + (size_t)hc * S_ * 384;
    K = 384;
    P = Pc + (size_t)hc * (size_t)S_ * S_;
    b = hc >> 1;
    cm = cmask + (size_t)b * S_ * S_;
    scl = sCul;
  }

  const f32x4 z4 = {0.f, 0.f, 0.f, 0.f};
  f32x4 acc[4][4];
#pragma unroll
  for (int i = 0; i < 4; ++i)
#pragma unroll
    for (int j = 0; j < 4; ++j) acc[i][j] = z4;

  const int sr = w * 32 + (lane >> 2);
  const int scp = lane & 3;

  for (int kt = 0; kt < K; kt += 32) {
    int r1 = sr, r2 = sr + 16;
    int c1 = (scp - (r1 >> 2)) & 3;
    int c2 = (scp - (r2 >> 2)) & 3;
    gld16(A + (size_t)(m0 + r1) * K + kt + c1 * 8, &lA[r1 * 32 + scp * 8]);
    gld16(A + (size_t)(m0 + r2) * K + kt + c2 * 8, &lA[r2 * 32 + scp * 8]);
    gld16(BT + (size_t)(n0 + r1) * K + kt + c1 * 8, &lB[r1 * 32 + scp * 8]);
    gld16(BT + (size_t)(n0 + r2) * K + kt + c2 * 8, &lB[r2 * 32 + scp * 8]);
    __syncthreads();
    short8 af[4], bg[4];
#pragma unroll
    for (int i = 0; i < 4; ++i) {
      int r = (w >> 1) * 64 + i * 16 + l15;
      af[i] = *reinterpret_cast<const short8*>(&lA[r * 32 + ((quad + (r >> 2)) & 3) * 8]);
    }
#pragma unroll
    for (int j = 0; j < 4; ++j) {
      int r = (w & 1) * 64 + j * 16 + l15;
      bg[j] = *reinterpret_cast<const short8*>(&lB[r * 32 + ((quad + (r >> 2)) & 3) * 8]);
    }
#pragma unroll
    for (int i = 0; i < 4; ++i)
#pragma unroll
      for (int j = 0; j < 4; ++j)
        acc[i][j] = __builtin_amdgcn_mfma_f32_16x16x32_bf16(af[i], bg[j], acc[i][j], 0, 0, 0);
    __syncthreads();
  }

  // epilogue: p = exp2(acc*scl + am[k]*l2e (+ cm[q][k]*l2e) - M), packed stores
  const float* amb = am + b * S_;
  float lsum[4] = {0.f, 0.f, 0.f, 0.f};
#pragma unroll
  for (int i = 0; i < 4; ++i) {
    int kb = m0 + (w >> 1) * 64 + i * 16 + quad * 4;    // 4 consecutive keys
    float4 a4 = *reinterpret_cast<const float4*>(amb + kb);
    float pre0 = fmaf(a4.x, L2E_, -FML2_);
    float pre1 = fmaf(a4.y, L2E_, -FML2_);
    float pre2 = fmaf(a4.z, L2E_, -FML2_);
    float pre3 = fmaf(a4.w, L2E_, -FML2_);
#pragma unroll
    for (int j = 0; j < 4; ++j) {
      int q = n0 + (w & 1) * 64 + j * 16 + l15;
      float c0 = pre0, c1 = pre1, c2 = pre2, c3 = pre3;
      if (cm) {
        float4 cmv = *reinterpret_cast<const float4*>(cm + (size_t)q * S_ + kb);
        c0 = fmaf(cmv.x, L2E_, c0);
        c1 = fmaf(cmv.y, L2E_, c1);
        c2 = fmaf(cmv.z, L2E_, c2);
        c3 = fmaf(cmv.w, L2E_, c3);
      }
      float p0 = exp2f(fmaf(acc[i][j][0], scl, c0));
      float p1 = exp2f(fmaf(acc[i][j][1], scl, c1));
      float p2 = exp2f(fmaf(acc[i][j][2], scl, c2));
      float p3 = exp2f(fmaf(acc[i][j][3], scl, c3));
      lsum[j] += (p0 + p1) + (p2 + p3);
      *reinterpret_cast<uint2*>(P + (size_t)q * S_ + kb) =
          make_uint2(pk2(p0, p1), pk2(p2, p3));
    }
  }
#pragma unroll
  for (int j = 0; j < 4; ++j) {
    float s = lsum[j];
    s += __shfl_xor(s, 16);
    s += __shfl_xor(s, 32);
    if (lane < 16)
      Lp[(size_t)gz * (32 * S_) + ((size_t)((m0 >> 7) * 2 + (w >> 1))) * S_ +
         n0 + (w & 1) * 64 + j * 16 + lane] = s;
  }
}

// ---------------- attention g2 (transposed): O^T[d][q] = Vt·P^T ----------------
// A = Vt (M=HD), BT = P[q][k] natural (N=queries), K = S_. Normalize by 1/l[q],
// write packed uint2 into AO[token][feature] (4 consecutive features).
__global__ __launch_bounds__(256) void attn_g2_k(
    const u16* __restrict__ Pr, const u16* __restrict__ Pc,
    const u16* __restrict__ Vtr, const u16* __restrict__ Vtc,
    const float* __restrict__ Lp, u16* __restrict__ AO, int zoff) {
  const int gz = zoff + blockIdx.z;
  const int m0 = blockIdx.y * 128, n0 = blockIdx.x * 128;  // m=feat, n=query
  const u16 *A, *BT;
  int b, colbase;
  if (gz < 12) {
    if (blockIdx.y) return;  // M = 128
    A = Vtr + (size_t)gz * 128 * S_;
    BT = Pr + (size_t)blockIdx.z * (size_t)S_ * S_;
    b = gz / 6;
    colbase = (gz % 6) * 128;
  } else {
    int hc = gz - 12;
    A = Vtc + (size_t)hc * 384 * S_;
    BT = Pc + (size_t)hc * (size_t)S_ * S_;
    b = hc >> 1;
    colbase = 768 + (hc & 1) * 384;
  }
  __shared__ u16 lA[128 * 32];
  __shared__ u16 lB[128 * 32];
  __shared__ float lL[128];
  const int tid = threadIdx.x, w = tid >> 6, lane = tid & 63;
  const int quad = lane >> 4, l15 = lane & 15;

  if (tid < 128) {
    const float* lp = Lp + (size_t)gz * (32 * S_) + (n0 + tid);
    float s = 0.f;
#pragma unroll
    for (int g = 0; g < 32; ++g) s += lp[(size_t)g * S_];
    lL[tid] = 1.f / s;
  }

  const f32x4 z4 = {0.f, 0.f, 0.f, 0.f};
  f32x4 acc[4][4];
#pragma unroll
  for (int i = 0; i < 4; ++i)
#pragma unroll
    for (int j = 0; j < 4; ++j) acc[i][j] = z4;

  const int sr = w * 32 + (lane >> 2);
  const int scp = lane & 3;

  for (int kt = 0; kt < S_; kt += 32) {
    int r1 = sr, r2 = sr + 16;
    int c1 = (scp - (r1 >> 2)) & 3;
    int c2 = (scp - (r2 >> 2)) & 3;
    gld16(A + (size_t)(m0 + r1) * S_ + kt + c1 * 8, &lA[r1 * 32 + scp * 8]);
    gld16(A + (size_t)(m0 + r2) * S_ + kt + c2 * 8, &lA[r2 * 32 + scp * 8]);
    gld16(BT + (size_t)(n0 + r1) * S_ + kt + c1 * 8, &lB[r1 * 32 + scp * 8]);
    gld16(BT + (size_t)(n0 + r2) * S_ + kt + c2 * 8, &lB[r2 * 32 + scp * 8]);
    __syncthreads();
    short8 af[4], bg[4];
#pragma unroll
    for (int i = 0; i < 4; ++i) {
      int r = (w >> 1) * 64 + i * 16 + l15;
      af[i] = *reinterpret_cast<const short8*>(&lA[r * 32 + ((quad + (r >> 2)) & 3) * 8]);
    }
#pragma unroll
    for (int j = 0; j < 4; ++j) {
      int r = (w & 1) * 64 + j * 16 + l15;
      bg[j] = *reinterpret_cast<const short8*>(&lB[r * 32 + ((quad + (r >> 2)) & 3) * 8]);
    }
#pragma unroll
    for (int i = 0; i < 4; ++i)
#pragma unroll
      for (int j = 0; j < 4; ++j)
        acc[i][j] = __builtin_amdgcn_mfma_f32_16x16x32_bf16(af[i], bg[j], acc[i][j], 0, 0, 0);
    __syncthreads();
  }

  float invl[4];
#pragma unroll
  for (int j = 0; j < 4; ++j) invl[j] = lL[(w & 1) * 64 + j * 16 + l15];
#pragma unroll
  for (int i = 0; i < 4; ++i) {
    int feat = colbase + m0 + (w >> 1) * 64 + i * 16 + quad * 4;
#pragma unroll
    for (int j = 0; j < 4; ++j) {
      int q = n0 + (w & 1) * 64 + j * 16 + l15;
      float v0 = acc[i][j][0] * invl[j];
      float v1 = acc[i][j][1] * invl[j];
      float v2 = acc[i][j][2] * invl[j];
      float v3 = acc[i][j][3] * invl[j];
      *reinterpret_cast<uint2*>(AO + ((size_t)(b * S_ + q)) * 1536 + feat) =
          make_uint2(pk2(v0, v1), pk2(v2, v3));
    }
  }
}

// ---------------- launcher ----------------

extern "C" void kernel_launch(void* const* d_in, const int* in_sizes, int n_in,
                              void* d_out, int out_size, void* d_ws, size_t ws_size,
                              hipStream_t stream) {
  const float* x     = (const float*)d_in[0];
  const float* cmask = (const float*)d_in[1];
  const float* amask = (const float*)d_in[2];
  const float* W[8]  = { (const float*)d_in[3], (const float*)d_in[4], (const float*)d_in[5],
                         (const float*)d_in[6], (const float*)d_in[7], (const float*)d_in[8],
                         (const float*)d_in[9], (const float*)d_in[10] };
  const float* rq_b = (const float*)d_in[11];
  const float* rk_b = (const float*)d_in[12];
  const float* rv_b = (const float*)d_in[13];
  const float* ro_b = (const float*)d_in[14];
  const float* cq_b = (const float*)d_in[15];
  const float* ck_b = (const float*)d_in[16];
  const float* cv_b = (const float*)d_in[17];
  const float* co_b = (const float*)d_in[18];
  const float* r_cb = (const float*)d_in[19];
  const float* c_cb = (const float*)d_in[20];
  const float* out_w = (const float*)d_in[21];
  const float* out_b = (const float*)d_in[22];

  char* p = (char*)d_ws;
  auto carve = [&](size_t bytes) -> void* {
    void* r = (void*)p;
    p += (bytes + 255) & ~(size_t)255;
    return r;
  };
  u16* Xb    = (u16*)carve((size_t)BS_ * E_ * 2);       // dead after QKV gemm
  u16* WqkvT = (u16*)carve((size_t)4608 * 768 * 2);     // dead after QKV gemm
  u16* outwT = (u16*)carve((size_t)768 * 1536 * 2);
  u16* Wrc   = (u16*)carve((size_t)1536 * 768 * 2);     // [ro_w;co_w] bf16 straight
  u16* WfT   = (u16*)carve((size_t)768 * 1536 * 2);     // fused proj weight
  float* bqkv   = (float*)carve(4608 * 4);
  float* bzero  = (float*)carve(1536 * 4);
  float* bfused = (float*)carve(768 * 4);
  u16* Qr  = (u16*)carve((size_t)B_ * 6 * S_ * 128 * 2);
  u16* Kr  = (u16*)carve((size_t)B_ * 6 * S_ * 128 * 2);
  u16* Vtr = (u16*)carve((size_t)B_ * 6 * S_ * 128 * 2);
  u16* Qc  = (u16*)carve((size_t)B_ * 2 * S_ * 384 * 2);
  u16* Kc  = (u16*)carve((size_t)B_ * 2 * S_ * 384 * 2);
  u16* Vtc = (u16*)carve((size_t)B_ * 2 * S_ * 384 * 2);
  u16* AO  = (u16*)carve((size_t)BS_ * 1536 * 2);

  // Lp aliases dead Xb region (4.2 MB <= 6.3 MB).
  float* Lp = (float*)Xb;
  u16* Pcul = (u16*)carve((size_t)4 * S_ * S_ * 2);     // 33.6 MB
  size_t used = (size_t)(p - (char*)d_ws);
  size_t rem = (ws_size > used) ? (ws_size - used) : 0;
  int RCH;                                              // regular heads per chunk
  if      (rem >= (size_t)12 * S_ * S_ * 2 + 4096) RCH = 12;
  else if (rem >= (size_t)4  * S_ * S_ * 2 + 4096) RCH = 4;
  else                                             RCH = 2;
  u16* Preg = (u16*)carve((size_t)RCH * S_ * S_ * 2);

  const float sReg = 0.08838834764831845f * L2E_;
  const float sCul = 0.05103103630798288f * L2E_;

  // ---- single preprocessing launch ----
  PrepP pp;
  pp.x = x; pp.Xb = Xb;
  pp.row = W[3]; pp.cow = W[7]; pp.Wrc = Wrc;
  const int wsel[6] = {0, 1, 2, 4, 5, 6};  // rq rk rv cq ck cv
  for (int i = 0; i < 6; ++i) {
    pp.tsrc[i] = W[wsel[i]];
    pp.tdst[i] = WqkvT + (size_t)i * 768 * 768;
    pp.trows[i] = 768;
  }
  pp.tsrc[6] = out_w; pp.tdst[6] = outwT; pp.trows[6] = 1536;
  pp.rqb = rq_b; pp.rkb = rk_b; pp.rvb = rv_b;
  pp.cqb = cq_b; pp.ckb = ck_b; pp.cvb = cv_b;
  pp.rcb = r_cb; pp.ccb = c_cb;
  pp.bqkv = bqkv; pp.bzero = bzero;
  prep_k<<<dim3(8856), 256, 0, stream>>>(pp);

  // fused output bias (reads outwT produced by prep_k)
  bfused_k<<<dim3(3), 256, 0, stream>>>(outwT, out_b, ro_b, co_b, bfused);

  // ---- fused projection weight: WfT[of][if] = sum_m Wrc[if][m] * out_w[m + sel*768][of]
  // M=if(1536), N=of(768), K=768; msplit trick keeps A=Wrc, shifts outwT cols by 768.
  gemm_t_k<0><<<dim3(6, 12), 256, 0, stream>>>(
      Wrc, 768, outwT, 1536, bzero, 768,
      Wrc + (size_t)768 * 768, 768, 768, (void*)WfT, 1536,
      nullptr, nullptr, nullptr, nullptr, nullptr, nullptr);

  // fused QKV projection, transposed: M=4608 features, N=4096 tokens
  gemm_t_k<2><<<dim3(32, 36), 256, 0, stream>>>(
      WqkvT, 768, Xb, 768, bqkv, 768,
      (const u16*)nullptr, 0, 0, (void*)nullptr, 0,
      Qr, Kr, Vtr, Qc, Kc, Vtc);

  if (RCH == 12) {
    attn_g1_k<<<dim3(16, 16, 16), 256, 0, stream>>>(
        Qr, Kr, Qc, Kc, Preg, Pcul, Lp, amask, cmask, sReg, sCul, 0);
    attn_g2_k<<<dim3(16, 3, 16), 256, 0, stream>>>(
        Preg, Pcul, Vtr, Vtc, Lp, AO, 0);
  } else {
    attn_g1_k<<<dim3(16, 16, 4), 256, 0, stream>>>(
        Qr, Kr, Qc, Kc, Preg, Pcul, Lp, amask, cmask, sReg, sCul, 12);
    attn_g2_k<<<dim3(16, 3, 4), 256, 0, stream>>>(
        Preg, Pcul, Vtr, Vtc, Lp, AO, 12);
    for (int c = 0; c < 12; c += RCH) {
      attn_g1_k<<<dim3(16, 16, RCH), 256, 0, stream>>>(
          Qr, Kr, Qc, Kc, Preg, Pcul, Lp, amask, cmask, sReg, sCul, c);
      attn_g2_k<<<dim3(16, 1, RCH), 256, 0, stream>>>(
          Preg, Pcul, Vtr, Vtc, Lp, AO, c);
    }
  }

  // final fused projection: M=768 out-features, N=4096 tokens, K=1536
  gemm_t_k<1><<<dim3(32, 6), 256, 0, stream>>>(
      WfT, 1536, AO, 1536, bfused, 1536,
      (const u16*)nullptr, 0, 0, d_out, 768,
      nullptr, nullptr, nullptr, nullptr, nullptr, nullptr);
}

// Round 6
// 402.410 us; speedup vs baseline: 2.2701x; 1.0562x over previous
//
#include <hip/hip_runtime.h>
#include <hip/hip_bf16.h>

using u16 = unsigned short;
using u32 = unsigned int;
typedef short short8 __attribute__((ext_vector_type(8)));
typedef float f32x4 __attribute__((ext_vector_type(4)));

#define B_  2
#define S_  2048
#define E_  768
#define BS_ 4096

#define L2E_ 1.44269504088896f
#define FML2_ 17.3123404906676f   // 12.0 * log2(e) fixed softmax stabilizer

__device__ __forceinline__ u16 f2bf(float f) {
  __hip_bfloat16 h = __float2bfloat16(f);
  return *reinterpret_cast<u16*>(&h);
}

__device__ __forceinline__ u32 pk2(float a, float b) {
  return (u32)f2bf(a) | ((u32)f2bf(b) << 16);
}

// async global->LDS, 16B per lane. LDS dest must be wave-uniform base + lane*16.
__device__ __forceinline__ void gld16(const void* g, void* l) {
  __builtin_amdgcn_global_load_lds(
      (const __attribute__((address_space(1))) u32*)g,
      (__attribute__((address_space(3))) u32*)l, 16, 0, 0);
}

// ---------------- fused preprocessing: conv-x | conv-weights | transposes |
// biases. One launch; block ranges select the task. ----------------
struct PrepP {
  const float* x;  u16* Xb;
  const float* row; const float* cow; u16* Wrc;   // [ro_w;co_w] -> bf16 straight
  const float* tsrc[7]; u16* tdst[7]; int trows[7];
  const float* rqb; const float* rkb; const float* rvb;
  const float* cqb; const float* ckb; const float* cvb;
  const float* rcb; const float* ccb;
  float* bqkv; float* bzero;
};

__global__ __launch_bounds__(256) void prep_k(PrepP p) {
  const int bid = blockIdx.x, tid = threadIdx.x;
  __shared__ float tsh[32][33];
  if (bid < 3072) {                       // x -> Xb bf16 (786432 float4s)
    int i = bid * 256 + tid;
    float4 v = reinterpret_cast<const float4*>(p.x)[i];
    reinterpret_cast<uint2*>(p.Xb)[i] = make_uint2(pk2(v.x, v.y), pk2(v.z, v.w));
  } else if (bid < 4224) {                // [ro_w;co_w] -> Wrc bf16 (294912 f4)
    int i = (bid - 3072) * 256 + tid;
    const float* s = (i < 147456) ? p.row : p.cow;
    int k = (i < 147456) ? i : i - 147456;
    float4 v = reinterpret_cast<const float4*>(s)[k];
    reinterpret_cast<uint2*>(p.Wrc)[i] = make_uint2(pk2(v.x, v.y), pk2(v.z, v.w));
  } else if (bid < 8832) {                // transposes: 6x(24x24) + 1x(48x24)
    int tb = bid - 4224;
    int mi, ty, tx;
    if (tb < 3456) { mi = tb / 576; int r = tb - mi * 576; ty = r / 24; tx = r - ty * 24; }
    else           { int r = tb - 3456; mi = 6; ty = r / 24; tx = r - ty * 24; }
    const float* src = p.tsrc[mi];
    u16* dst = p.tdst[mi];
    const int rows = p.trows[mi];
    const int r0 = ty * 32, c0 = tx * 32;
    const int txx = tid & 31, tyy = tid >> 5;
#pragma unroll
    for (int d = 0; d < 4; ++d) {
      int r = tyy + d * 8;
      tsh[r][txx] = src[(size_t)(r0 + r) * 768 + c0 + txx];
    }
    __syncthreads();
#pragma unroll
    for (int d = 0; d < 4; ++d) {
      int c = tyy + d * 8;
      dst[(size_t)(c0 + c) * rows + r0 + txx] = f2bf(tsh[txx][c]);
    }
  } else {                                // bqkv + bzero (24 blocks)
    int t = (bid - 8832) * 256 + tid;
    if (t < 4608) {
      int seg = t / 768, i = t - seg * 768;
      float v = 0.f;
      if      (seg == 0) v = p.rqb[i] + p.rcb[i];   // cultural bias folds into Q bias
      else if (seg == 1) v = p.rkb[i];
      else if (seg == 2) v = p.rvb[i];
      else if (seg == 3) v = p.cqb[i] + p.ccb[i];
      else if (seg == 4) v = p.ckb[i];
      else               v = p.cvb[i];
      p.bqkv[t] = v;
    } else if (t < 6144) {
      p.bzero[t - 4608] = 0.f;
    }
  }
}

// bfused[of] = out_b[of] + sum_m [ro_b;co_b][m] * out_w[m][of].
// One WAVE per output feature: lane l covers elements [24l, 24l+24) of the
// contiguous outwT row (3 aligned short8 loads, all independent), rcb staged
// in LDS, 6-step shfl butterfly. 192 blocks -> fully parallel, ~2 us.
__global__ __launch_bounds__(256) void bfused_k(
    const u16* __restrict__ outwT, const float* __restrict__ out_b,
    const float* __restrict__ ro_b, const float* __restrict__ co_b,
    float* __restrict__ bfused) {
  __shared__ float rcb[1536];
  const int tid = threadIdx.x, w = tid >> 6, lane = tid & 63;
  for (int i = tid; i < 768; i += 256) {
    rcb[i] = ro_b[i];
    rcb[768 + i] = co_b[i];
  }
  __syncthreads();
  const int of = blockIdx.x * 4 + w;                // grid 192 -> of in [0,768)
  const u16* row = outwT + (size_t)of * 1536 + lane * 24;
  const float* rc = rcb + lane * 24;
  float a0 = 0.f, a1 = 0.f, a2 = 0.f, a3 = 0.f;
#pragma unroll
  for (int g = 0; g < 3; ++g) {
    short8 v = *reinterpret_cast<const short8*>(row + g * 8);
    u32 b0 = ((u32)(u16)v[0]) << 16, b1 = ((u32)(u16)v[1]) << 16;
    u32 b2 = ((u32)(u16)v[2]) << 16, b3 = ((u32)(u16)v[3]) << 16;
    u32 b4 = ((u32)(u16)v[4]) << 16, b5 = ((u32)(u16)v[5]) << 16;
    u32 b6 = ((u32)(u16)v[6]) << 16, b7 = ((u32)(u16)v[7]) << 16;
    a0 = fmaf(*reinterpret_cast<float*>(&b0), rc[g * 8 + 0], a0);
    a1 = fmaf(*reinterpret_cast<float*>(&b1), rc[g * 8 + 1], a1);
    a2 = fmaf(*reinterpret_cast<float*>(&b2), rc[g * 8 + 2], a2);
    a3 = fmaf(*reinterpret_cast<float*>(&b3), rc[g * 8 + 3], a3);
    a0 = fmaf(*reinterpret_cast<float*>(&b4), rc[g * 8 + 4], a0);
    a1 = fmaf(*reinterpret_cast<float*>(&b5), rc[g * 8 + 5], a1);
    a2 = fmaf(*reinterpret_cast<float*>(&b6), rc[g * 8 + 6], a2);
    a3 = fmaf(*reinterpret_cast<float*>(&b7), rc[g * 8 + 7], a3);
  }
  float s = (a0 + a1) + (a2 + a3);
  s += __shfl_xor(s, 1);
  s += __shfl_xor(s, 2);
  s += __shfl_xor(s, 4);
  s += __shfl_xor(s, 8);
  s += __shfl_xor(s, 16);
  s += __shfl_xor(s, 32);
  if (lane == 0) bfused[of] = s + out_b[of];
}

// ============ transposed GEMM: computes C^T, i.e. C[row=M][col=N] with
// A[M][K], BT[N][K]; lane's 4 acc values are CONSECUTIVE M-rows -> packed
// 8B stores. MODE 0: PROJ (bf16 -> Cout[col*ldc+row], m-split A select)
// MODE 1: FINAL (fp32 float4 -> Cout[col*ldc+row])
// MODE 2: QKVT routing (M=feature, N=token) ============

template<int MODE>
__global__ __launch_bounds__(256) void gemm_t_k(
    const u16* __restrict__ A, int lda,
    const u16* __restrict__ BT, int ldb,
    const float* __restrict__ bias, int K,
    const u16* __restrict__ A2, int msplit, int bofs,
    void* __restrict__ Cout, int ldc,
    u16* __restrict__ Qr, u16* __restrict__ Kr, u16* __restrict__ Vtr,
    u16* __restrict__ Qc, u16* __restrict__ Kc, u16* __restrict__ Vtc) {
  __shared__ u16 lA[128 * 32];
  __shared__ u16 lB[128 * 32];
  const int tid = threadIdx.x, w = tid >> 6, lane = tid & 63;
  const int quad = lane >> 4, l15 = lane & 15;
  const int m0 = blockIdx.y * 128, n0 = blockIdx.x * 128;
  if (msplit && m0 >= msplit) { A = A2 - (size_t)msplit * lda; BT += bofs; }

  const f32x4 z4 = {0.f, 0.f, 0.f, 0.f};
  f32x4 acc[4][4];
#pragma unroll
  for (int i = 0; i < 4; ++i)
#pragma unroll
    for (int j = 0; j < 4; ++j) acc[i][j] = z4;

  const int sr = w * 32 + (lane >> 2);
  const int scp = lane & 3;

  for (int kt = 0; kt < K; kt += 32) {
    int r1 = sr, r2 = sr + 16;
    int c1 = (scp - (r1 >> 2)) & 3;
    int c2 = (scp - (r2 >> 2)) & 3;
    gld16(A + (size_t)(m0 + r1) * lda + kt + c1 * 8, &lA[r1 * 32 + scp * 8]);
    gld16(A + (size_t)(m0 + r2) * lda + kt + c2 * 8, &lA[r2 * 32 + scp * 8]);
    gld16(BT + (size_t)(n0 + r1) * ldb + kt + c1 * 8, &lB[r1 * 32 + scp * 8]);
    gld16(BT + (size_t)(n0 + r2) * ldb + kt + c2 * 8, &lB[r2 * 32 + scp * 8]);
    __syncthreads();
    short8 af[4], bg[4];
#pragma unroll
    for (int i = 0; i < 4; ++i) {
      int r = (w >> 1) * 64 + i * 16 + l15;
      af[i] = *reinterpret_cast<const short8*>(&lA[r * 32 + ((quad + (r >> 2)) & 3) * 8]);
    }
#pragma unroll
    for (int j = 0; j < 4; ++j) {
      int r = (w & 1) * 64 + j * 16 + l15;
      bg[j] = *reinterpret_cast<const short8*>(&lB[r * 32 + ((quad + (r >> 2)) & 3) * 8]);
    }
#pragma unroll
    for (int i = 0; i < 4; ++i)
#pragma unroll
      for (int j = 0; j < 4; ++j)
        acc[i][j] = __builtin_amdgcn_mfma_f32_16x16x32_bf16(af[i], bg[j], acc[i][j], 0, 0, 0);
    __syncthreads();
  }

  const int seg = (MODE == 2) ? (m0 / 768) : 0;
#pragma unroll
  for (int i = 0; i < 4; ++i) {
    int f = m0 + (w >> 1) * 64 + i * 16 + quad * 4;   // M-row base (4 consecutive)
    float4 b4 = *reinterpret_cast<const float4*>(bias + f);
#pragma unroll
    for (int j = 0; j < 4; ++j) {
      int t = n0 + (w & 1) * 64 + j * 16 + l15;        // N-col
      float v0 = acc[i][j][0] + b4.x;
      float v1 = acc[i][j][1] + b4.y;
      float v2 = acc[i][j][2] + b4.z;
      float v3 = acc[i][j][3] + b4.w;
      if (MODE == 0) {
        *reinterpret_cast<uint2*>((u16*)Cout + (size_t)t * ldc + f) =
            make_uint2(pk2(v0, v1), pk2(v2, v3));
      } else if (MODE == 1) {
        *reinterpret_cast<float4*>((float*)Cout + (size_t)t * ldc + f) =
            make_float4(v0, v1, v2, v3);
      } else {
        int b = t >> 11, s = t & 2047;
        int fs = f - seg * 768;
        if (seg == 0) {
          int h = fs >> 7, d = fs & 127;
          *reinterpret_cast<uint2*>(Qr + ((size_t)(b * 6 + h) * 2048 + s) * 128 + d) =
              make_uint2(pk2(v0, v1), pk2(v2, v3));
        } else if (seg == 1) {
          int h = fs >> 7, d = fs & 127;
          *reinterpret_cast<uint2*>(Kr + ((size_t)(b * 6 + h) * 2048 + s) * 128 + d) =
              make_uint2(pk2(v0, v1), pk2(v2, v3));
        } else if (seg == 2) {
          int h = fs >> 7, d = fs & 127;
          u16* vp = Vtr + ((size_t)(b * 6 + h) * 128 + d) * 2048 + s;
          vp[0] = f2bf(v0); vp[2048] = f2bf(v1); vp[4096] = f2bf(v2); vp[6144] = f2bf(v3);
        } else if (seg == 3) {
          int h = fs / 384, d = fs - h * 384;
          *reinterpret_cast<uint2*>(Qc + ((size_t)(b * 2 + h) * 2048 + s) * 384 + d) =
              make_uint2(pk2(v0, v1), pk2(v2, v3));
        } else if (seg == 4) {
          int h = fs / 384, d = fs - h * 384;
          *reinterpret_cast<uint2*>(Kc + ((size_t)(b * 2 + h) * 2048 + s) * 384 + d) =
              make_uint2(pk2(v0, v1), pk2(v2, v3));
        } else {
          int h = fs / 384, d = fs - h * 384;
          u16* vp = Vtc + ((size_t)(b * 2 + h) * 384 + d) * 2048 + s;
          vp[0] = f2bf(v0); vp[2048] = f2bf(v1); vp[4096] = f2bf(v2); vp[6144] = f2bf(v3);
        }
      }
    }
  }
}

// ---------------- attention g1 (transposed): S^T[k][q] = K·Q^T ----------------
// A = K-matrix (M=keys), BT = Q-matrix (N=queries); lane's 4 values are
// consecutive KEYS -> P[q][k] written as packed uint2; cm/am as float4 loads.
// Row-sums over keys: 2 shfl_xor + 32-partial Lp[gz][32][S].
__global__ __launch_bounds__(256) void attn_g1_k(
    const u16* __restrict__ Qr, const u16* __restrict__ Kr,
    const u16* __restrict__ Qc, const u16* __restrict__ Kc,
    u16* __restrict__ Pr, u16* __restrict__ Pc, float* __restrict__ Lp,
    const float* __restrict__ am, const float* __restrict__ cmask,
    float sReg, float sCul, int zoff) {
  __shared__ u16 lA[128 * 32];
  __shared__ u16 lB[128 * 32];
  const int tid = threadIdx.x, w = tid >> 6, lane = tid & 63;
  const int quad = lane >> 4, l15 = lane & 15;
  const int m0 = blockIdx.y * 128, n0 = blockIdx.x * 128;  // m=key, n=query
  const int gz = zoff + blockIdx.z;
  const u16 *A, *BT;
  u16* P;
  const float* cm = nullptr;
  float scl;
  int K, b;
  if (gz < 12) {
    A = Kr + (size_t)gz * S_ * 128;
    BT = Qr + (size_t)gz * S_ * 128;
    K = 128;
    P = Pr + (size_t)blockIdx.z * (size_t)S_ * S_;
    scl = sReg;
    b = gz / 6;
  } else {
    int hc = gz - 12;
    A = Kc + (size_t)hc * S_ * 384;
    BT = Qc + (size_t)hc * S_ * 384;
    K = 384;
    P = Pc + (size_t)hc * (size_t)S_ * S_;
    b = hc >> 1;
    cm = cmask + (size_t)b * S_ * S_;
    scl = sCul;
  }

  const f32x4 z4 = {0.f, 0.f, 0.f, 0.f};
  f32x4 acc[4][4];
#pragma unroll
  for (int i = 0; i < 4; ++i)
#pragma unroll
    for (int j = 0; j < 4; ++j) acc[i][j] = z4;

  const int sr = w * 32 + (lane >> 2);
  const int scp = lane & 3;

  for (int kt = 0; kt < K; kt += 32) {
    int r1 = sr, r2 = sr + 16;
    int c1 = (scp - (r1 >> 2)) & 3;
    int c2 = (scp - (r2 >> 2)) & 3;
    gld16(A + (size_t)(m0 + r1) * K + kt + c1 * 8, &lA[r1 * 32 + scp * 8]);
    gld16(A + (size_t)(m0 + r2) * K + kt + c2 * 8, &lA[r2 * 32 + scp * 8]);
    gld16(BT + (size_t)(n0 + r1) * K + kt + c1 * 8, &lB[r1 * 32 + scp * 8]);
    gld16(BT + (size_t)(n0 + r2) * K + kt + c2 * 8, &lB[r2 * 32 + scp * 8]);
    __syncthreads();
    short8 af[4], bg[4];
#pragma unroll
    for (int i = 0; i < 4; ++i) {
      int r = (w >> 1) * 64 + i * 16 + l15;
      af[i] = *reinterpret_cast<const short8*>(&lA[r * 32 + ((quad + (r >> 2)) & 3) * 8]);
    }
#pragma unroll
    for (int j = 0; j < 4; ++j) {
      int r = (w & 1) * 64 + j * 16 + l15;
      bg[j] = *reinterpret_cast<const short8*>(&lB[r * 32 + ((quad + (r >> 2)) & 3) * 8]);
    }
#pragma unroll
    for (int i = 0; i < 4; ++i)
#pragma unroll
      for (int j = 0; j < 4; ++j)
        acc[i][j] = __builtin_amdgcn_mfma_f32_16x16x32_bf16(af[i], bg[j], acc[i][j], 0, 0, 0);
    __syncthreads();
  }

  // epilogue: p = exp2(acc*scl + am[k]*l2e (+ cm[q][k]*l2e) - M), packed stores
  const float* amb = am + b * S_;
  float lsum[4] = {0.f, 0.f, 0.f, 0.f};
#pragma unroll
  for (int i = 0; i < 4; ++i) {
    int kb = m0 + (w >> 1) * 64 + i * 16 + quad * 4;    // 4 consecutive keys
    float4 a4 = *reinterpret_cast<const float4*>(amb + kb);
    float pre0 = fmaf(a4.x, L2E_, -FML2_);
    float pre1 = fmaf(a4.y, L2E_, -FML2_);
    float pre2 = fmaf(a4.z, L2E_, -FML2_);
    float pre3 = fmaf(a4.w, L2E_, -FML2_);
#pragma unroll
    for (int j = 0; j < 4; ++j) {
      int q = n0 + (w & 1) * 64 + j * 16 + l15;
      float c0 = pre0, c1 = pre1, c2 = pre2, c3 = pre3;
      if (cm) {
        float4 cmv = *reinterpret_cast<const float4*>(cm + (size_t)q * S_ + kb);
        c0 = fmaf(cmv.x, L2E_, c0);
        c1 = fmaf(cmv.y, L2E_, c1);
        c2 = fmaf(cmv.z, L2E_, c2);
        c3 = fmaf(cmv.w, L2E_, c3);
      }
      float p0 = exp2f(fmaf(acc[i][j][0], scl, c0));
      float p1 = exp2f(fmaf(acc[i][j][1], scl, c1));
      float p2 = exp2f(fmaf(acc[i][j][2], scl, c2));
      float p3 = exp2f(fmaf(acc[i][j][3], scl, c3));
      lsum[j] += (p0 + p1) + (p2 + p3);
      *reinterpret_cast<uint2*>(P + (size_t)q * S_ + kb) =
          make_uint2(pk2(p0, p1), pk2(p2, p3));
    }
  }
#pragma unroll
  for (int j = 0; j < 4; ++j) {
    float s = lsum[j];
    s += __shfl_xor(s, 16);
    s += __shfl_xor(s, 32);
    if (lane < 16)
      Lp[(size_t)gz * (32 * S_) + ((size_t)((m0 >> 7) * 2 + (w >> 1))) * S_ +
         n0 + (w & 1) * 64 + j * 16 + lane] = s;
  }
}

// ---------------- attention g2 (transposed): O^T[d][q] = Vt·P^T ----------------
// A = Vt (M=HD), BT = P[q][k] natural (N=queries), K = S_. Normalize by 1/l[q],
// write packed uint2 into AO[token][feature] (4 consecutive features).
__global__ __launch_bounds__(256) void attn_g2_k(
    const u16* __restrict__ Pr, const u16* __restrict__ Pc,
    const u16* __restrict__ Vtr, const u16* __restrict__ Vtc,
    const float* __restrict__ Lp, u16* __restrict__ AO, int zoff) {
  const int gz = zoff + blockIdx.z;
  const int m0 = blockIdx.y * 128, n0 = blockIdx.x * 128;  // m=feat, n=query
  const u16 *A, *BT;
  int b, colbase;
  if (gz < 12) {
    if (blockIdx.y) return;  // M = 128
    A = Vtr + (size_t)gz * 128 * S_;
    BT = Pr + (size_t)blockIdx.z * (size_t)S_ * S_;
    b = gz / 6;
    colbase = (gz % 6) * 128;
  } else {
    int hc = gz - 12;
    A = Vtc + (size_t)hc * 384 * S_;
    BT = Pc + (size_t)hc * (size_t)S_ * S_;
    b = hc >> 1;
    colbase = 768 + (hc & 1) * 384;
  }
  __shared__ u16 lA[128 * 32];
  __shared__ u16 lB[128 * 32];
  __shared__ float lL[128];
  const int tid = threadIdx.x, w = tid >> 6, lane = tid & 63;
  const int quad = lane >> 4, l15 = lane & 15;

  if (tid < 128) {
    const float* lp = Lp + (size_t)gz * (32 * S_) + (n0 + tid);
    float s = 0.f;
#pragma unroll
    for (int g = 0; g < 32; ++g) s += lp[(size_t)g * S_];
    lL[tid] = 1.f / s;
  }

  const f32x4 z4 = {0.f, 0.f, 0.f, 0.f};
  f32x4 acc[4][4];
#pragma unroll
  for (int i = 0; i < 4; ++i)
#pragma unroll
    for (int j = 0; j < 4; ++j) acc[i][j] = z4;

  const int sr = w * 32 + (lane >> 2);
  const int scp = lane & 3;

  for (int kt = 0; kt < S_; kt += 32) {
    int r1 = sr, r2 = sr + 16;
    int c1 = (scp - (r1 >> 2)) & 3;
    int c2 = (scp - (r2 >> 2)) & 3;
    gld16(A + (size_t)(m0 + r1) * S_ + kt + c1 * 8, &lA[r1 * 32 + scp * 8]);
    gld16(A + (size_t)(m0 + r2) * S_ + kt + c2 * 8, &lA[r2 * 32 + scp * 8]);
    gld16(BT + (size_t)(n0 + r1) * S_ + kt + c1 * 8, &lB[r1 * 32 + scp * 8]);
    gld16(BT + (size_t)(n0 + r2) * S_ + kt + c2 * 8, &lB[r2 * 32 + scp * 8]);
    __syncthreads();
    short8 af[4], bg[4];
#pragma unroll
    for (int i = 0; i < 4; ++i) {
      int r = (w >> 1) * 64 + i * 16 + l15;
      af[i] = *reinterpret_cast<const short8*>(&lA[r * 32 + ((quad + (r >> 2)) & 3) * 8]);
    }
#pragma unroll
    for (int j = 0; j < 4; ++j) {
      int r = (w & 1) * 64 + j * 16 + l15;
      bg[j] = *reinterpret_cast<const short8*>(&lB[r * 32 + ((quad + (r >> 2)) & 3) * 8]);
    }
#pragma unroll
    for (int i = 0; i < 4; ++i)
#pragma unroll
      for (int j = 0; j < 4; ++j)
        acc[i][j] = __builtin_amdgcn_mfma_f32_16x16x32_bf16(af[i], bg[j], acc[i][j], 0, 0, 0);
    __syncthreads();
  }

  float invl[4];
#pragma unroll
  for (int j = 0; j < 4; ++j) invl[j] = lL[(w & 1) * 64 + j * 16 + l15];
#pragma unroll
  for (int i = 0; i < 4; ++i) {
    int feat = colbase + m0 + (w >> 1) * 64 + i * 16 + quad * 4;
#pragma unroll
    for (int j = 0; j < 4; ++j) {
      int q = n0 + (w & 1) * 64 + j * 16 + l15;
      float v0 = acc[i][j][0] * invl[j];
      float v1 = acc[i][j][1] * invl[j];
      float v2 = acc[i][j][2] * invl[j];
      float v3 = acc[i][j][3] * invl[j];
      *reinterpret_cast<uint2*>(AO + ((size_t)(b * S_ + q)) * 1536 + feat) =
          make_uint2(pk2(v0, v1), pk2(v2, v3));
    }
  }
}

// ---------------- launcher ----------------

extern "C" void kernel_launch(void* const* d_in, const int* in_sizes, int n_in,
                              void* d_out, int out_size, void* d_ws, size_t ws_size,
                              hipStream_t stream) {
  const float* x     = (const float*)d_in[0];
  const float* cmask = (const float*)d_in[1];
  const float* amask = (const float*)d_in[2];
  const float* W[8]  = { (const float*)d_in[3], (const float*)d_in[4], (const float*)d_in[5],
                         (const float*)d_in[6], (const float*)d_in[7], (const float*)d_in[8],
                         (const float*)d_in[9], (const float*)d_in[10] };
  const float* rq_b = (const float*)d_in[11];
  const float* rk_b = (const float*)d_in[12];
  const float* rv_b = (const float*)d_in[13];
  const float* ro_b = (const float*)d_in[14];
  const float* cq_b = (const float*)d_in[15];
  const float* ck_b = (const float*)d_in[16];
  const float* cv_b = (const float*)d_in[17];
  const float* co_b = (const float*)d_in[18];
  const float* r_cb = (const float*)d_in[19];
  const float* c_cb = (const float*)d_in[20];
  const float* out_w = (const float*)d_in[21];
  const float* out_b = (const float*)d_in[22];

  char* p = (char*)d_ws;
  auto carve = [&](size_t bytes) -> void* {
    void* r = (void*)p;
    p += (bytes + 255) & ~(size_t)255;
    return r;
  };
  u16* Xb    = (u16*)carve((size_t)BS_ * E_ * 2);       // dead after QKV gemm
  u16* WqkvT = (u16*)carve((size_t)4608 * 768 * 2);     // dead after QKV gemm
  u16* outwT = (u16*)carve((size_t)768 * 1536 * 2);
  u16* Wrc   = (u16*)carve((size_t)1536 * 768 * 2);     // [ro_w;co_w] bf16 straight
  u16* WfT   = (u16*)carve((size_t)768 * 1536 * 2);     // fused proj weight
  float* bqkv   = (float*)carve(4608 * 4);
  float* bzero  = (float*)carve(1536 * 4);
  float* bfused = (float*)carve(768 * 4);
  u16* Qr  = (u16*)carve((size_t)B_ * 6 * S_ * 128 * 2);
  u16* Kr  = (u16*)carve((size_t)B_ * 6 * S_ * 128 * 2);
  u16* Vtr = (u16*)carve((size_t)B_ * 6 * S_ * 128 * 2);
  u16* Qc  = (u16*)carve((size_t)B_ * 2 * S_ * 384 * 2);
  u16* Kc  = (u16*)carve((size_t)B_ * 2 * S_ * 384 * 2);
  u16* Vtc = (u16*)carve((size_t)B_ * 2 * S_ * 384 * 2);
  u16* AO  = (u16*)carve((size_t)BS_ * 1536 * 2);

  // Lp aliases dead Xb region (4.2 MB <= 6.3 MB).
  float* Lp = (float*)Xb;
  u16* Pcul = (u16*)carve((size_t)4 * S_ * S_ * 2);     // 33.6 MB
  size_t used = (size_t)(p - (char*)d_ws);
  size_t rem = (ws_size > used) ? (ws_size - used) : 0;
  int RCH;                                              // regular heads per chunk
  if      (rem >= (size_t)12 * S_ * S_ * 2 + 4096) RCH = 12;
  else if (rem >= (size_t)4  * S_ * S_ * 2 + 4096) RCH = 4;
  else                                             RCH = 2;
  u16* Preg = (u16*)carve((size_t)RCH * S_ * S_ * 2);

  const float sReg = 0.08838834764831845f * L2E_;
  const float sCul = 0.05103103630798288f * L2E_;

  // ---- single preprocessing launch ----
  PrepP pp;
  pp.x = x; pp.Xb = Xb;
  pp.row = W[3]; pp.cow = W[7]; pp.Wrc = Wrc;
  const int wsel[6] = {0, 1, 2, 4, 5, 6};  // rq rk rv cq ck cv
  for (int i = 0; i < 6; ++i) {
    pp.tsrc[i] = W[wsel[i]];
    pp.tdst[i] = WqkvT + (size_t)i * 768 * 768;
    pp.trows[i] = 768;
  }
  pp.tsrc[6] = out_w; pp.tdst[6] = outwT; pp.trows[6] = 1536;
  pp.rqb = rq_b; pp.rkb = rk_b; pp.rvb = rv_b;
  pp.cqb = cq_b; pp.ckb = ck_b; pp.cvb = cv_b;
  pp.rcb = r_cb; pp.ccb = c_cb;
  pp.bqkv = bqkv; pp.bzero = bzero;
  prep_k<<<dim3(8856), 256, 0, stream>>>(pp);

  // fused output bias (reads outwT produced by prep_k; 1 wave per feature)
  bfused_k<<<dim3(192), 256, 0, stream>>>(outwT, out_b, ro_b, co_b, bfused);

  // ---- fused projection weight: WfT[of][if] = sum_m Wrc[if][m] * out_w[m + sel*768][of]
  // M=if(1536), N=of(768), K=768; msplit trick keeps A=Wrc, shifts outwT cols by 768.
  gemm_t_k<0><<<dim3(6, 12), 256, 0, stream>>>(
      Wrc, 768, outwT, 1536, bzero, 768,
      Wrc + (size_t)768 * 768, 768, 768, (void*)WfT, 1536,
      nullptr, nullptr, nullptr, nullptr, nullptr, nullptr);

  // fused QKV projection, transposed: M=4608 features, N=4096 tokens
  gemm_t_k<2><<<dim3(32, 36), 256, 0, stream>>>(
      WqkvT, 768, Xb, 768, bqkv, 768,
      (const u16*)nullptr, 0, 0, (void*)nullptr, 0,
      Qr, Kr, Vtr, Qc, Kc, Vtc);

  if (RCH == 12) {
    attn_g1_k<<<dim3(16, 16, 16), 256, 0, stream>>>(
        Qr, Kr, Qc, Kc, Preg, Pcul, Lp, amask, cmask, sReg, sCul, 0);
    attn_g2_k<<<dim3(16, 3, 16), 256, 0, stream>>>(
        Preg, Pcul, Vtr, Vtc, Lp, AO, 0);
  } else {
    attn_g1_k<<<dim3(16, 16, 4), 256, 0, stream>>>(
        Qr, Kr, Qc, Kc, Preg, Pcul, Lp, amask, cmask, sReg, sCul, 12);
    attn_g2_k<<<dim3(16, 3, 4), 256, 0, stream>>>(
        Preg, Pcul, Vtr, Vtc, Lp, AO, 12);
    for (int c = 0; c < 12; c += RCH) {
      attn_g1_k<<<dim3(16, 16, RCH), 256, 0, stream>>>(
          Qr, Kr, Qc, Kc, Preg, Pcul, Lp, amask, cmask, sReg, sCul, c);
      attn_g2_k<<<dim3(16, 1, RCH), 256, 0, stream>>>(
          Preg, Pcul, Vtr, Vtc, Lp, AO, c);
    }
  }

  // final fused projection: M=768 out-features, N=4096 tokens, K=1536
  gemm_t_k<1><<<dim3(32, 6), 256, 0, stream>>>(
      WfT, 1536, AO, 1536, bfused, 1536,
      (const u16*)nullptr, 0, 0, d_out, 768,
      nullptr, nullptr, nullptr, nullptr, nullptr, nullptr);
}

// Round 7
// 379.023 us; speedup vs baseline: 2.4102x; 1.0617x over previous
//
#include <hip/hip_runtime.h>
#include <hip/hip_bf16.h>

using u16 = unsigned short;
using u32 = unsigned int;
typedef short short8 __attribute__((ext_vector_type(8)));
typedef float f32x4 __attribute__((ext_vector_type(4)));

#define B_  2
#define S_  2048
#define E_  768
#define BS_ 4096

#define L2E_ 1.44269504088896f
#define FML2_ 17.3123404906676f   // 12.0 * log2(e) fixed softmax stabilizer

__device__ __forceinline__ u16 f2bf(float f) {
  __hip_bfloat16 h = __float2bfloat16(f);
  return *reinterpret_cast<u16*>(&h);
}

__device__ __forceinline__ u32 pk2(float a, float b) {
  return (u32)f2bf(a) | ((u32)f2bf(b) << 16);
}

// async global->LDS, 16B per lane. LDS dest must be wave-uniform base + lane*16.
__device__ __forceinline__ void gld16(const void* g, void* l) {
  __builtin_amdgcn_global_load_lds(
      (const __attribute__((address_space(1))) u32*)g,
      (__attribute__((address_space(3))) u32*)l, 16, 0, 0);
}

// ---- [128][64] bf16 tile staging with XOR-involution swizzle ----
// stored[row][slot] = src[row][slot ^ (row&7)] (8 slots of 8 u16 = 16B).
// LDS dest is linear (wave-uniform base + lane*16B); source pre-swizzled.
__device__ __forceinline__ void stage64(const u16* __restrict__ src, int srcStride,
                                        u16* buf, int w, int lane) {
  const int rl = lane >> 3;          // row offset within 8-row group
  const int cg0 = lane & 7;          // stored 16B slot
#pragma unroll
  for (int it = 0; it < 4; ++it) {
    int r0 = w * 32 + it * 8;
    int row = r0 + rl;
    int cg = cg0 ^ (row & 7);        // pre-swizzled source col-group
    gld16(src + (size_t)row * srcStride + cg * 8, buf + r0 * 64 + lane * 8);
  }
}

// read 8 consecutive bf16 at k-offset kt + quad*8 from row r (undoes the XOR)
__device__ __forceinline__ short8 rdfrag64(const u16* buf, int r, int kt, int quad) {
  int slot = (((kt >> 3) + quad) ^ (r & 7)) & 7;
  return *reinterpret_cast<const short8*>(buf + r * 64 + slot * 8);
}

// ---------------- fused preprocessing: conv-x | conv-weights | transposes |
// biases. One launch; block ranges select the task. ----------------
struct PrepP {
  const float* x;  u16* Xb;
  const float* row; const float* cow; u16* Wrc;   // [ro_w;co_w] -> bf16 straight
  const float* tsrc[7]; u16* tdst[7]; int trows[7];
  const float* rqb; const float* rkb; const float* rvb;
  const float* cqb; const float* ckb; const float* cvb;
  const float* rcb; const float* ccb;
  float* bqkv; float* bzero;
};

__global__ __launch_bounds__(256) void prep_k(PrepP p) {
  const int bid = blockIdx.x, tid = threadIdx.x;
  __shared__ float tsh[32][33];
  if (bid < 3072) {                       // x -> Xb bf16 (786432 float4s)
    int i = bid * 256 + tid;
    float4 v = reinterpret_cast<const float4*>(p.x)[i];
    reinterpret_cast<uint2*>(p.Xb)[i] = make_uint2(pk2(v.x, v.y), pk2(v.z, v.w));
  } else if (bid < 4224) {                // [ro_w;co_w] -> Wrc bf16 (294912 f4)
    int i = (bid - 3072) * 256 + tid;
    const float* s = (i < 147456) ? p.row : p.cow;
    int k = (i < 147456) ? i : i - 147456;
    float4 v = reinterpret_cast<const float4*>(s)[k];
    reinterpret_cast<uint2*>(p.Wrc)[i] = make_uint2(pk2(v.x, v.y), pk2(v.z, v.w));
  } else if (bid < 8832) {                // transposes: 6x(24x24) + 1x(48x24)
    int tb = bid - 4224;
    int mi, ty, tx;
    if (tb < 3456) { mi = tb / 576; int r = tb - mi * 576; ty = r / 24; tx = r - ty * 24; }
    else           { int r = tb - 3456; mi = 6; ty = r / 24; tx = r - ty * 24; }
    const float* src = p.tsrc[mi];
    u16* dst = p.tdst[mi];
    const int rows = p.trows[mi];
    const int r0 = ty * 32, c0 = tx * 32;
    const int txx = tid & 31, tyy = tid >> 5;
#pragma unroll
    for (int d = 0; d < 4; ++d) {
      int r = tyy + d * 8;
      tsh[r][txx] = src[(size_t)(r0 + r) * 768 + c0 + txx];
    }
    __syncthreads();
#pragma unroll
    for (int d = 0; d < 4; ++d) {
      int c = tyy + d * 8;
      dst[(size_t)(c0 + c) * rows + r0 + txx] = f2bf(tsh[txx][c]);
    }
  } else {                                // bqkv + bzero (24 blocks)
    int t = (bid - 8832) * 256 + tid;
    if (t < 4608) {
      int seg = t / 768, i = t - seg * 768;
      float v = 0.f;
      if      (seg == 0) v = p.rqb[i] + p.rcb[i];   // cultural bias folds into Q bias
      else if (seg == 1) v = p.rkb[i];
      else if (seg == 2) v = p.rvb[i];
      else if (seg == 3) v = p.cqb[i] + p.ccb[i];
      else if (seg == 4) v = p.ckb[i];
      else               v = p.cvb[i];
      p.bqkv[t] = v;
    } else if (t < 6144) {
      p.bzero[t - 4608] = 0.f;
    }
  }
}

// bfused[of] = out_b[of] + sum_m [ro_b;co_b][m] * out_w[m][of].
// One WAVE per output feature: lane l covers elements [24l, 24l+24) of the
// contiguous outwT row (3 aligned short8 loads, all independent), rcb staged
// in LDS, 6-step shfl butterfly. 192 blocks -> fully parallel, ~2 us.
__global__ __launch_bounds__(256) void bfused_k(
    const u16* __restrict__ outwT, const float* __restrict__ out_b,
    const float* __restrict__ ro_b, const float* __restrict__ co_b,
    float* __restrict__ bfused) {
  __shared__ float rcb[1536];
  const int tid = threadIdx.x, w = tid >> 6, lane = tid & 63;
  for (int i = tid; i < 768; i += 256) {
    rcb[i] = ro_b[i];
    rcb[768 + i] = co_b[i];
  }
  __syncthreads();
  const int of = blockIdx.x * 4 + w;                // grid 192 -> of in [0,768)
  const u16* row = outwT + (size_t)of * 1536 + lane * 24;
  const float* rc = rcb + lane * 24;
  float a0 = 0.f, a1 = 0.f, a2 = 0.f, a3 = 0.f;
#pragma unroll
  for (int g = 0; g < 3; ++g) {
    short8 v = *reinterpret_cast<const short8*>(row + g * 8);
    u32 b0 = ((u32)(u16)v[0]) << 16, b1 = ((u32)(u16)v[1]) << 16;
    u32 b2 = ((u32)(u16)v[2]) << 16, b3 = ((u32)(u16)v[3]) << 16;
    u32 b4 = ((u32)(u16)v[4]) << 16, b5 = ((u32)(u16)v[5]) << 16;
    u32 b6 = ((u32)(u16)v[6]) << 16, b7 = ((u32)(u16)v[7]) << 16;
    a0 = fmaf(*reinterpret_cast<float*>(&b0), rc[g * 8 + 0], a0);
    a1 = fmaf(*reinterpret_cast<float*>(&b1), rc[g * 8 + 1], a1);
    a2 = fmaf(*reinterpret_cast<float*>(&b2), rc[g * 8 + 2], a2);
    a3 = fmaf(*reinterpret_cast<float*>(&b3), rc[g * 8 + 3], a3);
    a0 = fmaf(*reinterpret_cast<float*>(&b4), rc[g * 8 + 4], a0);
    a1 = fmaf(*reinterpret_cast<float*>(&b5), rc[g * 8 + 5], a1);
    a2 = fmaf(*reinterpret_cast<float*>(&b6), rc[g * 8 + 6], a2);
    a3 = fmaf(*reinterpret_cast<float*>(&b7), rc[g * 8 + 7], a3);
  }
  float s = (a0 + a1) + (a2 + a3);
  s += __shfl_xor(s, 1);
  s += __shfl_xor(s, 2);
  s += __shfl_xor(s, 4);
  s += __shfl_xor(s, 8);
  s += __shfl_xor(s, 16);
  s += __shfl_xor(s, 32);
  if (lane == 0) bfused[of] = s + out_b[of];
}

// ============ transposed GEMM: computes C^T, i.e. C[row=M][col=N] with
// A[M][K], BT[N][K]; lane's 4 acc values are CONSECUTIVE M-rows -> packed
// 8B stores. BK=64 whole-tile staging (2 barriers / 64-K-step).
// MODE 0: PROJ (bf16 -> Cout[col*ldc+row], m-split A select)
// MODE 1: FINAL (fp32 float4 -> Cout[col*ldc+row])
// MODE 2: QKVT routing (M=feature, N=token) ============

template<int MODE>
__global__ __launch_bounds__(256) void gemm_t_k(
    const u16* __restrict__ A, int lda,
    const u16* __restrict__ BT, int ldb,
    const float* __restrict__ bias, int K,
    const u16* __restrict__ A2, int msplit, int bofs,
    void* __restrict__ Cout, int ldc,
    u16* __restrict__ Qr, u16* __restrict__ Kr, u16* __restrict__ Vtr,
    u16* __restrict__ Qc, u16* __restrict__ Kc, u16* __restrict__ Vtc) {
  __shared__ __align__(16) u16 lA[128 * 64];
  __shared__ __align__(16) u16 lB[128 * 64];
  const int tid = threadIdx.x, w = tid >> 6, lane = tid & 63;
  const int quad = lane >> 4, l15 = lane & 15;
  const int m0 = blockIdx.y * 128, n0 = blockIdx.x * 128;
  if (msplit && m0 >= msplit) { A = A2 - (size_t)msplit * lda; BT += bofs; }

  const f32x4 z4 = {0.f, 0.f, 0.f, 0.f};
  f32x4 acc[4][4];
#pragma unroll
  for (int i = 0; i < 4; ++i)
#pragma unroll
    for (int j = 0; j < 4; ++j) acc[i][j] = z4;

  for (int kc = 0; kc < K; kc += 64) {
    stage64(A + (size_t)m0 * lda + kc, lda, lA, w, lane);
    stage64(BT + (size_t)n0 * ldb + kc, ldb, lB, w, lane);
    __syncthreads();
#pragma unroll
    for (int kt = 0; kt < 64; kt += 32) {
      short8 af[4], bg[4];
#pragma unroll
      for (int i = 0; i < 4; ++i)
        af[i] = rdfrag64(lA, (w >> 1) * 64 + i * 16 + l15, kt, quad);
#pragma unroll
      for (int j = 0; j < 4; ++j)
        bg[j] = rdfrag64(lB, (w & 1) * 64 + j * 16 + l15, kt, quad);
#pragma unroll
      for (int i = 0; i < 4; ++i)
#pragma unroll
        for (int j = 0; j < 4; ++j)
          acc[i][j] = __builtin_amdgcn_mfma_f32_16x16x32_bf16(af[i], bg[j], acc[i][j], 0, 0, 0);
    }
    __syncthreads();
  }

  const int seg = (MODE == 2) ? (m0 / 768) : 0;
#pragma unroll
  for (int i = 0; i < 4; ++i) {
    int f = m0 + (w >> 1) * 64 + i * 16 + quad * 4;   // M-row base (4 consecutive)
    float4 b4 = *reinterpret_cast<const float4*>(bias + f);
#pragma unroll
    for (int j = 0; j < 4; ++j) {
      int t = n0 + (w & 1) * 64 + j * 16 + l15;        // N-col
      float v0 = acc[i][j][0] + b4.x;
      float v1 = acc[i][j][1] + b4.y;
      float v2 = acc[i][j][2] + b4.z;
      float v3 = acc[i][j][3] + b4.w;
      if (MODE == 0) {
        *reinterpret_cast<uint2*>((u16*)Cout + (size_t)t * ldc + f) =
            make_uint2(pk2(v0, v1), pk2(v2, v3));
      } else if (MODE == 1) {
        *reinterpret_cast<float4*>((float*)Cout + (size_t)t * ldc + f) =
            make_float4(v0, v1, v2, v3);
      } else {
        int b = t >> 11, s = t & 2047;
        int fs = f - seg * 768;
        if (seg == 0) {
          int h = fs >> 7, d = fs & 127;
          *reinterpret_cast<uint2*>(Qr + ((size_t)(b * 6 + h) * 2048 + s) * 128 + d) =
              make_uint2(pk2(v0, v1), pk2(v2, v3));
        } else if (seg == 1) {
          int h = fs >> 7, d = fs & 127;
          *reinterpret_cast<uint2*>(Kr + ((size_t)(b * 6 + h) * 2048 + s) * 128 + d) =
              make_uint2(pk2(v0, v1), pk2(v2, v3));
        } else if (seg == 2) {
          int h = fs >> 7, d = fs & 127;
          u16* vp = Vtr + ((size_t)(b * 6 + h) * 128 + d) * 2048 + s;
          vp[0] = f2bf(v0); vp[2048] = f2bf(v1); vp[4096] = f2bf(v2); vp[6144] = f2bf(v3);
        } else if (seg == 3) {
          int h = fs / 384, d = fs - h * 384;
          *reinterpret_cast<uint2*>(Qc + ((size_t)(b * 2 + h) * 2048 + s) * 384 + d) =
              make_uint2(pk2(v0, v1), pk2(v2, v3));
        } else if (seg == 4) {
          int h = fs / 384, d = fs - h * 384;
          *reinterpret_cast<uint2*>(Kc + ((size_t)(b * 2 + h) * 2048 + s) * 384 + d) =
              make_uint2(pk2(v0, v1), pk2(v2, v3));
        } else {
          int h = fs / 384, d = fs - h * 384;
          u16* vp = Vtc + ((size_t)(b * 2 + h) * 384 + d) * 2048 + s;
          vp[0] = f2bf(v0); vp[2048] = f2bf(v1); vp[4096] = f2bf(v2); vp[6144] = f2bf(v3);
        }
      }
    }
  }
}

// ---------------- attention g1 (transposed): S^T[k][q] = K·Q^T ----------------
// A = K-matrix (M=keys), BT = Q-matrix (N=queries); lane's 4 values are
// consecutive KEYS -> P[q][k] written as packed uint2; cm/am as float4 loads.
// BK=64 staging: reg 4 barriers/block (was 8), cul 12 (was 24).
__global__ __launch_bounds__(256) void attn_g1_k(
    const u16* __restrict__ Qr, const u16* __restrict__ Kr,
    const u16* __restrict__ Qc, const u16* __restrict__ Kc,
    u16* __restrict__ Pr, u16* __restrict__ Pc, float* __restrict__ Lp,
    const float* __restrict__ am, const float* __restrict__ cmask,
    float sReg, float sCul, int zoff) {
  __shared__ __align__(16) u16 lA[128 * 64];
  __shared__ __align__(16) u16 lB[128 * 64];
  const int tid = threadIdx.x, w = tid >> 6, lane = tid & 63;
  const int quad = lane >> 4, l15 = lane & 15;
  const int m0 = blockIdx.y * 128, n0 = blockIdx.x * 128;  // m=key, n=query
  const int gz = zoff + blockIdx.z;
  const u16 *A, *BT;
  u16* P;
  const float* cm = nullptr;
  float scl;
  int K, b;
  if (gz < 12) {
    A = Kr + (size_t)gz * S_ * 128;
    BT = Qr + (size_t)gz * S_ * 128;
    K = 128;
    P = Pr + (size_t)blockIdx.z * (size_t)S_ * S_;
    scl = sReg;
    b = gz / 6;
  } else {
    int hc = gz - 12;
    A = Kc + (size_t)hc * S_ * 384;
    BT = Qc + (size_t)hc * S_ * 384;
    K = 384;
    P = Pc + (size_t)hc * (size_t)S_ * S_;
    b = hc >> 1;
    cm = cmask + (size_t)b * S_ * S_;
    scl = sCul;
  }

  const f32x4 z4 = {0.f, 0.f, 0.f, 0.f};
  f32x4 acc[4][4];
#pragma unroll
  for (int i = 0; i < 4; ++i)
#pragma unroll
    for (int j = 0; j < 4; ++j) acc[i][j] = z4;

  for (int kc = 0; kc < K; kc += 64) {
    stage64(A + (size_t)m0 * K + kc, K, lA, w, lane);
    stage64(BT + (size_t)n0 * K + kc, K, lB, w, lane);
    __syncthreads();
#pragma unroll
    for (int kt = 0; kt < 64; kt += 32) {
      short8 af[4], bg[4];
#pragma unroll
      for (int i = 0; i < 4; ++i)
        af[i] = rdfrag64(lA, (w >> 1) * 64 + i * 16 + l15, kt, quad);
#pragma unroll
      for (int j = 0; j < 4; ++j)
        bg[j] = rdfrag64(lB, (w & 1) * 64 + j * 16 + l15, kt, quad);
#pragma unroll
      for (int i = 0; i < 4; ++i)
#pragma unroll
        for (int j = 0; j < 4; ++j)
          acc[i][j] = __builtin_amdgcn_mfma_f32_16x16x32_bf16(af[i], bg[j], acc[i][j], 0, 0, 0);
    }
    __syncthreads();
  }

  // epilogue: p = exp2(acc*scl + am[k]*l2e (+ cm[q][k]*l2e) - M), packed stores
  const float* amb = am + b * S_;
  float lsum[4] = {0.f, 0.f, 0.f, 0.f};
#pragma unroll
  for (int i = 0; i < 4; ++i) {
    int kb = m0 + (w >> 1) * 64 + i * 16 + quad * 4;    // 4 consecutive keys
    float4 a4 = *reinterpret_cast<const float4*>(amb + kb);
    float pre0 = fmaf(a4.x, L2E_, -FML2_);
    float pre1 = fmaf(a4.y, L2E_, -FML2_);
    float pre2 = fmaf(a4.z, L2E_, -FML2_);
    float pre3 = fmaf(a4.w, L2E_, -FML2_);
#pragma unroll
    for (int j = 0; j < 4; ++j) {
      int q = n0 + (w & 1) * 64 + j * 16 + l15;
      float c0 = pre0, c1 = pre1, c2 = pre2, c3 = pre3;
      if (cm) {
        float4 cmv = *reinterpret_cast<const float4*>(cm + (size_t)q * S_ + kb);
        c0 = fmaf(cmv.x, L2E_, c0);
        c1 = fmaf(cmv.y, L2E_, c1);
        c2 = fmaf(cmv.z, L2E_, c2);
        c3 = fmaf(cmv.w, L2E_, c3);
      }
      float p0 = exp2f(fmaf(acc[i][j][0], scl, c0));
      float p1 = exp2f(fmaf(acc[i][j][1], scl, c1));
      float p2 = exp2f(fmaf(acc[i][j][2], scl, c2));
      float p3 = exp2f(fmaf(acc[i][j][3], scl, c3));
      lsum[j] += (p0 + p1) + (p2 + p3);
      *reinterpret_cast<uint2*>(P + (size_t)q * S_ + kb) =
          make_uint2(pk2(p0, p1), pk2(p2, p3));
    }
  }
#pragma unroll
  for (int j = 0; j < 4; ++j) {
    float s = lsum[j];
    s += __shfl_xor(s, 16);
    s += __shfl_xor(s, 32);
    if (lane < 16)
      Lp[(size_t)gz * (32 * S_) + ((size_t)((m0 >> 7) * 2 + (w >> 1))) * S_ +
         n0 + (w & 1) * 64 + j * 16 + lane] = s;
  }
}

// ---------------- attention g2 (transposed): O^T[d][q] = Vt·P^T ----------------
// A = Vt (M=HD), BT = P[q][k] natural (N=queries), K = S_. Normalize by 1/l[q],
// write packed uint2 into AO[token][feature]. BK=64: 64 barriers (was 128).
__global__ __launch_bounds__(256) void attn_g2_k(
    const u16* __restrict__ Pr, const u16* __restrict__ Pc,
    const u16* __restrict__ Vtr, const u16* __restrict__ Vtc,
    const float* __restrict__ Lp, u16* __restrict__ AO, int zoff) {
  const int gz = zoff + blockIdx.z;
  const int m0 = blockIdx.y * 128, n0 = blockIdx.x * 128;  // m=feat, n=query
  const u16 *A, *BT;
  int b, colbase;
  if (gz < 12) {
    if (blockIdx.y) return;  // M = 128
    A = Vtr + (size_t)gz * 128 * S_;
    BT = Pr + (size_t)blockIdx.z * (size_t)S_ * S_;
    b = gz / 6;
    colbase = (gz % 6) * 128;
  } else {
    int hc = gz - 12;
    A = Vtc + (size_t)hc * 384 * S_;
    BT = Pc + (size_t)hc * (size_t)S_ * S_;
    b = hc >> 1;
    colbase = 768 + (hc & 1) * 384;
  }
  __shared__ __align__(16) u16 lA[128 * 64];
  __shared__ __align__(16) u16 lB[128 * 64];
  __shared__ float lL[128];
  const int tid = threadIdx.x, w = tid >> 6, lane = tid & 63;
  const int quad = lane >> 4, l15 = lane & 15;

  if (tid < 128) {
    const float* lp = Lp + (size_t)gz * (32 * S_) + (n0 + tid);
    float s = 0.f;
#pragma unroll
    for (int g = 0; g < 32; ++g) s += lp[(size_t)g * S_];
    lL[tid] = 1.f / s;
  }

  const f32x4 z4 = {0.f, 0.f, 0.f, 0.f};
  f32x4 acc[4][4];
#pragma unroll
  for (int i = 0; i < 4; ++i)
#pragma unroll
    for (int j = 0; j < 4; ++j) acc[i][j] = z4;

  for (int kc = 0; kc < S_; kc += 64) {
    stage64(A + (size_t)m0 * S_ + kc, S_, lA, w, lane);
    stage64(BT + (size_t)n0 * S_ + kc, S_, lB, w, lane);
    __syncthreads();
#pragma unroll
    for (int kt = 0; kt < 64; kt += 32) {
      short8 af[4], bg[4];
#pragma unroll
      for (int i = 0; i < 4; ++i)
        af[i] = rdfrag64(lA, (w >> 1) * 64 + i * 16 + l15, kt, quad);
#pragma unroll
      for (int j = 0; j < 4; ++j)
        bg[j] = rdfrag64(lB, (w & 1) * 64 + j * 16 + l15, kt, quad);
#pragma unroll
      for (int i = 0; i < 4; ++i)
#pragma unroll
        for (int j = 0; j < 4; ++j)
          acc[i][j] = __builtin_amdgcn_mfma_f32_16x16x32_bf16(af[i], bg[j], acc[i][j], 0, 0, 0);
    }
    __syncthreads();
  }

  float invl[4];
#pragma unroll
  for (int j = 0; j < 4; ++j) invl[j] = lL[(w & 1) * 64 + j * 16 + l15];
#pragma unroll
  for (int i = 0; i < 4; ++i) {
    int feat = colbase + m0 + (w >> 1) * 64 + i * 16 + quad * 4;
#pragma unroll
    for (int j = 0; j < 4; ++j) {
      int q = n0 + (w & 1) * 64 + j * 16 + l15;
      float v0 = acc[i][j][0] * invl[j];
      float v1 = acc[i][j][1] * invl[j];
      float v2 = acc[i][j][2] * invl[j];
      float v3 = acc[i][j][3] * invl[j];
      *reinterpret_cast<uint2*>(AO + ((size_t)(b * S_ + q)) * 1536 + feat) =
          make_uint2(pk2(v0, v1), pk2(v2, v3));
    }
  }
}

// ---------------- launcher ----------------

extern "C" void kernel_launch(void* const* d_in, const int* in_sizes, int n_in,
                              void* d_out, int out_size, void* d_ws, size_t ws_size,
                              hipStream_t stream) {
  const float* x     = (const float*)d_in[0];
  const float* cmask = (const float*)d_in[1];
  const float* amask = (const float*)d_in[2];
  const float* W[8]  = { (const float*)d_in[3], (const float*)d_in[4], (const float*)d_in[5],
                         (const float*)d_in[6], (const float*)d_in[7], (const float*)d_in[8],
                         (const float*)d_in[9], (const float*)d_in[10] };
  const float* rq_b = (const float*)d_in[11];
  const float* rk_b = (const float*)d_in[12];
  const float* rv_b = (const float*)d_in[13];
  const float* ro_b = (const float*)d_in[14];
  const float* cq_b = (const float*)d_in[15];
  const float* ck_b = (const float*)d_in[16];
  const float* cv_b = (const float*)d_in[17];
  const float* co_b = (const float*)d_in[18];
  const float* r_cb = (const float*)d_in[19];
  const float* c_cb = (const float*)d_in[20];
  const float* out_w = (const float*)d_in[21];
  const float* out_b = (const float*)d_in[22];

  char* p = (char*)d_ws;
  auto carve = [&](size_t bytes) -> void* {
    void* r = (void*)p;
    p += (bytes + 255) & ~(size_t)255;
    return r;
  };
  u16* Xb    = (u16*)carve((size_t)BS_ * E_ * 2);       // dead after QKV gemm
  u16* WqkvT = (u16*)carve((size_t)4608 * 768 * 2);     // dead after QKV gemm
  u16* outwT = (u16*)carve((size_t)768 * 1536 * 2);
  u16* Wrc   = (u16*)carve((size_t)1536 * 768 * 2);     // [ro_w;co_w] bf16 straight
  u16* WfT   = (u16*)carve((size_t)768 * 1536 * 2);     // fused proj weight
  float* bqkv   = (float*)carve(4608 * 4);
  float* bzero  = (float*)carve(1536 * 4);
  float* bfused = (float*)carve(768 * 4);
  u16* Qr  = (u16*)carve((size_t)B_ * 6 * S_ * 128 * 2);
  u16* Kr  = (u16*)carve((size_t)B_ * 6 * S_ * 128 * 2);
  u16* Vtr = (u16*)carve((size_t)B_ * 6 * S_ * 128 * 2);
  u16* Qc  = (u16*)carve((size_t)B_ * 2 * S_ * 384 * 2);
  u16* Kc  = (u16*)carve((size_t)B_ * 2 * S_ * 384 * 2);
  u16* Vtc = (u16*)carve((size_t)B_ * 2 * S_ * 384 * 2);
  u16* AO  = (u16*)carve((size_t)BS_ * 1536 * 2);

  // Lp aliases dead Xb region (4.2 MB <= 6.3 MB).
  float* Lp = (float*)Xb;
  u16* Pcul = (u16*)carve((size_t)4 * S_ * S_ * 2);     // 33.6 MB
  size_t used = (size_t)(p - (char*)d_ws);
  size_t rem = (ws_size > used) ? (ws_size - used) : 0;
  int RCH;                                              // regular heads per chunk
  if      (rem >= (size_t)12 * S_ * S_ * 2 + 4096) RCH = 12;
  else if (rem >= (size_t)4  * S_ * S_ * 2 + 4096) RCH = 4;
  else                                             RCH = 2;
  u16* Preg = (u16*)carve((size_t)RCH * S_ * S_ * 2);

  const float sReg = 0.08838834764831845f * L2E_;
  const float sCul = 0.05103103630798288f * L2E_;

  // ---- single preprocessing launch ----
  PrepP pp;
  pp.x = x; pp.Xb = Xb;
  pp.row = W[3]; pp.cow = W[7]; pp.Wrc = Wrc;
  const int wsel[6] = {0, 1, 2, 4, 5, 6};  // rq rk rv cq ck cv
  for (int i = 0; i < 6; ++i) {
    pp.tsrc[i] = W[wsel[i]];
    pp.tdst[i] = WqkvT + (size_t)i * 768 * 768;
    pp.trows[i] = 768;
  }
  pp.tsrc[6] = out_w; pp.tdst[6] = outwT; pp.trows[6] = 1536;
  pp.rqb = rq_b; pp.rkb = rk_b; pp.rvb = rv_b;
  pp.cqb = cq_b; pp.ckb = ck_b; pp.cvb = cv_b;
  pp.rcb = r_cb; pp.ccb = c_cb;
  pp.bqkv = bqkv; pp.bzero = bzero;
  prep_k<<<dim3(8856), 256, 0, stream>>>(pp);

  // fused output bias (reads outwT produced by prep_k; 1 wave per feature)
  bfused_k<<<dim3(192), 256, 0, stream>>>(outwT, out_b, ro_b, co_b, bfused);

  // ---- fused projection weight: WfT[of][if] = sum_m Wrc[if][m] * out_w[m + sel*768][of]
  // M=if(1536), N=of(768), K=768; msplit trick keeps A=Wrc, shifts outwT cols by 768.
  gemm_t_k<0><<<dim3(6, 12), 256, 0, stream>>>(
      Wrc, 768, outwT, 1536, bzero, 768,
      Wrc + (size_t)768 * 768, 768, 768, (void*)WfT, 1536,
      nullptr, nullptr, nullptr, nullptr, nullptr, nullptr);

  // fused QKV projection, transposed: M=4608 features, N=4096 tokens
  gemm_t_k<2><<<dim3(32, 36), 256, 0, stream>>>(
      WqkvT, 768, Xb, 768, bqkv, 768,
      (const u16*)nullptr, 0, 0, (void*)nullptr, 0,
      Qr, Kr, Vtr, Qc, Kc, Vtc);

  if (RCH == 12) {
    attn_g1_k<<<dim3(16, 16, 16), 256, 0, stream>>>(
        Qr, Kr, Qc, Kc, Preg, Pcul, Lp, amask, cmask, sReg, sCul, 0);
    attn_g2_k<<<dim3(16, 3, 16), 256, 0, stream>>>(
        Preg, Pcul, Vtr, Vtc, Lp, AO, 0);
  } else {
    attn_g1_k<<<dim3(16, 16, 4), 256, 0, stream>>>(
        Qr, Kr, Qc, Kc, Preg, Pcul, Lp, amask, cmask, sReg, sCul, 12);
    attn_g2_k<<<dim3(16, 3, 4), 256, 0, stream>>>(
        Preg, Pcul, Vtr, Vtc, Lp, AO, 12);
    for (int c = 0; c < 12; c += RCH) {
      attn_g1_k<<<dim3(16, 16, RCH), 256, 0, stream>>>(
          Qr, Kr, Qc, Kc, Preg, Pcul, Lp, amask, cmask, sReg, sCul, c);
      attn_g2_k<<<dim3(16, 1, RCH), 256, 0, stream>>>(
          Preg, Pcul, Vtr, Vtc, Lp, AO, c);
    }
  }

  // final fused projection: M=768 out-features, N=4096 tokens, K=1536
  gemm_t_k<1><<<dim3(32, 6), 256, 0, stream>>>(
      WfT, 1536, AO, 1536, bfused, 1536,
      (const u16*)nullptr, 0, 0, d_out, 768,
      nullptr, nullptr, nullptr, nullptr, nullptr, nullptr);
}